// Round 11
// baseline (10264.816 us; speedup 1.0000x reference)
//
#include <hip/hip_runtime.h>
#include <stdint.h>

#define TT 128
#define BB 64
#define DD 1024
#define G3 3072

typedef unsigned short u16;
typedef unsigned int u32;
typedef __attribute__((ext_vector_type(8))) short bf16x8;
typedef __attribute__((ext_vector_type(4))) short s16x4;
typedef __attribute__((ext_vector_type(4))) float f32x4;

__device__ __forceinline__ float b2f(u16 h){ u32 u = ((u32)h)<<16; float f; __builtin_memcpy(&f,&u,4); return f; }
__device__ __forceinline__ u16 f2b(float f){ u32 u; __builtin_memcpy(&u,&f,4); u = (u + 0x7fffu + ((u>>16)&1u))>>16; return (u16)u; }
__device__ __forceinline__ float sigm(float x){ return 1.f/(1.f+__expf(-x)); }
__device__ __forceinline__ float tanh_(float x){
  if (x > 10.f) return 1.f;
  if (x < -10.f) return -1.f;
  float e = __expf(2.f*x); return (e-1.f)/(e+1.f);
}

struct DPar {
  const u16 *A1,*A2,*A3,*A4,*A5,*A6;   // bf16 weights
  const float* feat;
  u16 *ghist,*cb,*qsel0,*qsel1,*qnewb,*eb0,*eb1;
  float *scoresP;                       // [TT][64][BB] per-block score partials
  float *parties,*gf,*ef,*GIPa0,*GIPa1;
  const float *bihg,*bhhg,*bihp,*bhhp,*bihe,*bhhe,*watt;
  const int* spk;
  float* out;
};

// ---- A-fragment loaders (bf16 direct; fp32 converted in-flight) ----
__device__ __forceinline__ void loadA(bf16x8& d, const u16* p){ d = *(const bf16x8*)p; }
__device__ __forceinline__ void loadA(bf16x8& d, const float* p){
  f32x4 lo = *(const f32x4*)p;
  f32x4 hi = *(const f32x4*)(p + 4);
  #pragma unroll
  for (int i = 0; i < 4; ++i) { d[i] = (short)f2b(lo[i]); d[i+4] = (short)f2b(hi[i]); }
}

__device__ __forceinline__ void zeroAcc(f32x4 (&a)[4][3]) {
  #pragma unroll
  for (int i = 0; i < 4; ++i) {
    a[i][0] = (f32x4){0,0,0,0}; a[i][1] = (f32x4){0,0,0,0}; a[i][2] = (f32x4){0,0,0,0};
  }
}

// ---- per-wave GEMM: 4 batch-tiles x 3 gate-tiles, NK k-tiles, 4-deep prefetch ----
template<int NK, typename TA>
__device__ __forceinline__ void gemm3(const TA* __restrict__ Ab, int ldA,
    const u16* __restrict__ W0, const u16* __restrict__ W1, const u16* __restrict__ W2,
    f32x4 (&acc)[4][3]) {
  bf16x8 af[4][4], wf[4][3];
  #pragma unroll
  for (int i = 0; i < 3; ++i) {          // preload 3 tiles (NK >= 8 always)
    const int ko = i * 32;
    #pragma unroll
    for (int bt = 0; bt < 4; ++bt) loadA(af[i][bt], Ab + (size_t)bt*16*ldA + ko);
    wf[i][0] = *(const bf16x8*)(W0 + ko);
    wf[i][1] = *(const bf16x8*)(W1 + ko);
    wf[i][2] = *(const bf16x8*)(W2 + ko);
  }
  #pragma unroll
  for (int kt = 0; kt < NK; ++kt) {
    const int cur = kt & 3;
    const int pft = kt + 3;
    if (pft < NK) {
      const int nb = pft & 3;
      const int ko = pft * 32;
      #pragma unroll
      for (int bt = 0; bt < 4; ++bt) loadA(af[nb][bt], Ab + (size_t)bt*16*ldA + ko);
      wf[nb][0] = *(const bf16x8*)(W0 + ko);
      wf[nb][1] = *(const bf16x8*)(W1 + ko);
      wf[nb][2] = *(const bf16x8*)(W2 + ko);
    }
    #pragma unroll
    for (int bt = 0; bt < 4; ++bt) {
      acc[bt][0] = __builtin_amdgcn_mfma_f32_16x16x32_bf16(af[cur][bt], wf[cur][0], acc[bt][0], 0,0,0);
      acc[bt][1] = __builtin_amdgcn_mfma_f32_16x16x32_bf16(af[cur][bt], wf[cur][1], acc[bt][1], 0,0,0);
      acc[bt][2] = __builtin_amdgcn_mfma_f32_16x16x32_bf16(af[cur][bt], wf[cur][2], acc[bt][2], 0,0,0);
    }
  }
}

// ---- park (write) or accumulate (add) a wave's acc into LDS [64][48] ----
__device__ __forceinline__ void parkAcc48(float* L, f32x4 (&acc)[4][3], int l15, int l4, bool add) {
  #pragma unroll
  for (int bt = 0; bt < 4; ++bt)
    #pragma unroll
    for (int ci = 0; ci < 3; ++ci) {
      const int col = ci*16 + l15;
      #pragma unroll
      for (int q = 0; q < 4; ++q) {
        float* s = L + (bt*16 + l4*4 + q)*48 + col;
        if (add) *s += acc[bt][ci][q]; else *s = acc[bt][ci][q];
      }
    }
}

// ---- fused global GRU (64 blocks x 256 thr, 16 cols): 4-way-K GEMMs + combine ----
__device__ void fusedG(const DPar& p, int t, int bj, char* ldsraw) {
  float* LI0 = (float*)ldsraw;     // each region [64][48] f32 = 12 KB
  float* LI1 = LI0 + 3072;
  float* LH0 = LI1 + 3072;
  float* LH1 = LH0 + 3072;
  const int tid = (int)threadIdx.x;
  const int kq = tid >> 6;
  const int lane = tid & 63, l15 = lane & 15, l4 = lane >> 4;
  const int lofs = l4 * 8;
  const int j0 = bj * 16;
  const size_t r0 = (size_t)(j0 + l15);
  const u16* qsel = (t & 1) ? p.qsel1 : p.qsel0;
  f32x4 acc[4][3];
  zeroAcc(acc);
  { // i-part: X = [feat | qsel], K=2048 quarters of 512
    const int kw = (kq < 2) ? kq*512 : 1024 + (kq - 2)*512;
    const u16* W0 = p.A1 + (r0       )*2048 + kw + lofs;
    const u16* W1 = p.A1 + (r0 + 1024)*2048 + kw + lofs;
    const u16* W2 = p.A1 + (r0 + 2048)*2048 + kw + lofs;
    if (kq < 2) gemm3<16>(p.feat + (size_t)t*BB*DD + (size_t)l15*DD + kq*512 + lofs, DD, W0, W1, W2, acc);
    else        gemm3<16>(qsel + (size_t)l15*DD + (kq-2)*512 + lofs, DD, W0, W1, W2, acc);
  }
  if (kq == 1) parkAcc48(LI0, acc, l15, l4, false);
  if (kq == 3) parkAcc48(LI1, acc, l15, l4, false);
  __syncthreads();
  if (kq == 0) parkAcc48(LI0, acc, l15, l4, true);
  if (kq == 2) parkAcc48(LI1, acc, l15, l4, true);
  zeroAcc(acc);
  if (t) { // h-part: g_{t-1}, K=1024 quarters of 256
    const int kw = kq*256;
    const u16* W0 = p.A2 + (r0       )*1024 + kw + lofs;
    const u16* W1 = p.A2 + (r0 + 1024)*1024 + kw + lofs;
    const u16* W2 = p.A2 + (r0 + 2048)*1024 + kw + lofs;
    gemm3<8>(p.ghist + (size_t)(t-1)*BB*DD + (size_t)l15*DD + kw + lofs, DD, W0, W1, W2, acc);
  }
  if (kq == 1) parkAcc48(LH0, acc, l15, l4, false);
  if (kq == 3) parkAcc48(LH1, acc, l15, l4, false);
  __syncthreads();
  if (kq == 0) parkAcc48(LH0, acc, l15, l4, true);
  if (kq == 2) parkAcc48(LH1, acc, l15, l4, true);
  __syncthreads();
  if (tid < 128) {
    const int b = tid >> 1, jjb = (tid & 1) * 8;
    const float* i0 = LI0 + b*48; const float* i1 = LI1 + b*48;
    const float* h0 = LH0 + b*48; const float* h1 = LH1 + b*48;
    float gv8[8]; float scp = 0.f;
    #pragma unroll
    for (int i = 0; i < 8; ++i) {
      const int jj = jjb + i, j = j0 + jj;
      const float ir = i0[jj]    + i1[jj]    + p.bihg[j];
      const float iz = i0[16+jj] + i1[16+jj] + p.bihg[1024+j];
      const float in_= i0[32+jj] + i1[32+jj] + p.bihg[2048+j];
      const float hr = h0[jj]    + h1[jj]    + p.bhhg[j];
      const float hz = h0[16+jj] + h1[16+jj] + p.bhhg[1024+j];
      const float hn = h0[32+jj] + h1[32+jj] + p.bhhg[2048+j];
      const float r_ = sigm(ir + hr);
      const float z_ = sigm(iz + hz);
      const float n_ = tanh_(in_ + r_*hn);
      const float gp = p.gf[(size_t)b*DD + j];
      const float gv = (1.f - z_)*n_ + z_*gp;
      p.gf[(size_t)b*DD + j] = gv;
      gv8[i] = gv;
      scp += gv * p.watt[j];
    }
    bf16x8 hh;
    #pragma unroll
    for (int i = 0; i < 8; ++i) hh[i] = (short)f2b(gv8[i]);
    *(bf16x8*)(p.ghist + (size_t)t*BB*DD + (size_t)b*DD + j0 + jjb) = hh;
    scp += __shfl_xor(scp, 1);
    if ((tid & 1) == 0) p.scoresP[(size_t)t*64*BB + (size_t)bj*BB + b] = scp;
  }
}

// ---- fused emotion GRU (64 blocks x 256 thr, 16 cols): emotion step td = t-1 ----
__device__ void fusedE(const DPar& p, int t, int bj, char* ldsraw) {
  const int td = t - 1;
  float* LI0 = (float*)ldsraw;
  float* LI1 = LI0 + 3072;
  float* LH0 = LI1 + 3072;
  float* LH1 = LH0 + 3072;
  const int tid = (int)threadIdx.x;
  const int kq = tid >> 6;
  const int lane = tid & 63, l15 = lane & 15, l4 = lane >> 4;
  const int lofs = l4 * 8;
  const int j0 = bj * 16;
  const size_t r0 = (size_t)(j0 + l15);
  f32x4 acc[4][3];
  zeroAcc(acc);
  { // i-part: qnew_{td}, K=1024 quarters
    const int kw = kq*256;
    const u16* W0 = p.A5 + (r0       )*1024 + kw + lofs;
    const u16* W1 = p.A5 + (r0 + 1024)*1024 + kw + lofs;
    const u16* W2 = p.A5 + (r0 + 2048)*1024 + kw + lofs;
    gemm3<8>(p.qnewb + (size_t)l15*DD + kw + lofs, DD, W0, W1, W2, acc);
  }
  if (kq == 1) parkAcc48(LI0, acc, l15, l4, false);
  if (kq == 3) parkAcc48(LI1, acc, l15, l4, false);
  __syncthreads();
  if (kq == 0) parkAcc48(LI0, acc, l15, l4, true);
  if (kq == 2) parkAcc48(LI1, acc, l15, l4, true);
  zeroAcc(acc);
  if (td > 0) { // h-part: e_{td-1}
    const u16* ebr = (t & 1) ? p.eb1 : p.eb0;
    const int kw = kq*256;
    const u16* W0 = p.A6 + (r0       )*1024 + kw + lofs;
    const u16* W1 = p.A6 + (r0 + 1024)*1024 + kw + lofs;
    const u16* W2 = p.A6 + (r0 + 2048)*1024 + kw + lofs;
    gemm3<8>(ebr + (size_t)l15*DD + kw + lofs, DD, W0, W1, W2, acc);
  }
  if (kq == 1) parkAcc48(LH0, acc, l15, l4, false);
  if (kq == 3) parkAcc48(LH1, acc, l15, l4, false);
  __syncthreads();
  if (kq == 0) parkAcc48(LH0, acc, l15, l4, true);
  if (kq == 2) parkAcc48(LH1, acc, l15, l4, true);
  __syncthreads();
  if (tid < 128) {
    const int b = tid >> 1, jjb = (tid & 1) * 8;
    const float* i0 = LI0 + b*48; const float* i1 = LI1 + b*48;
    const float* h0 = LH0 + b*48; const float* h1 = LH1 + b*48;
    float ev8[8];
    #pragma unroll
    for (int i = 0; i < 8; ++i) {
      const int jj = jjb + i, j = j0 + jj;
      const float ir = i0[jj]    + i1[jj]    + p.bihe[j];
      const float iz = i0[16+jj] + i1[16+jj] + p.bihe[1024+j];
      const float in_= i0[32+jj] + i1[32+jj] + p.bihe[2048+j];
      const float hr = h0[jj]    + h1[jj]    + p.bhhe[j];
      const float hz = h0[16+jj] + h1[16+jj] + p.bhhe[1024+j];
      const float hn = h0[32+jj] + h1[32+jj] + p.bhhe[2048+j];
      const float r_ = sigm(ir + hr);
      const float z_ = sigm(iz + hz);
      const float n_ = tanh_(in_ + r_*hn);
      const float ep = p.ef[(size_t)b*DD + j];
      const float ev = (1.f - z_)*n_ + z_*ep;
      p.ef[(size_t)b*DD + j] = ev;
      ev8[i] = ev;
    }
    float* orow = p.out + (size_t)td*BB*DD + (size_t)b*DD + j0 + jjb;
    *(f32x4*)orow       = (f32x4){ev8[0], ev8[1], ev8[2], ev8[3]};
    *(f32x4*)(orow + 4) = (f32x4){ev8[4], ev8[5], ev8[6], ev8[7]};
    u16* ebw = ((t-1) & 1) ? p.eb1 : p.eb0;
    bf16x8 ee;
    #pragma unroll
    for (int i = 0; i < 8; ++i) ee[i] = (short)f2b(ev8[i]);
    *(bf16x8*)(ebw + (size_t)b*DD + j0 + jjb) = ee;
  }
}

// ---- attention (64 blocks x 256 thr, one per batch): c_t from history < t ----
__device__ void attn_run(const DPar& p, int t, int b, float* smem) {
  float* al = smem;          // [128] alpha
  float* rs = smem + 128;    // [4] wave partials
  float* part = smem + 160;  // [4][64][16]
  const int tid = (int)threadIdx.x;
  float s = -1e30f;
  if (tid < t) {
    const float* sp = p.scoresP + (size_t)tid*(64*BB) + b;
    float a0 = 0.f;
    #pragma unroll
    for (int pp = 0; pp < 64; ++pp) a0 += sp[pp*BB];
    s = a0;
  }
  if (tid < 128) {
    float m = s;
    #pragma unroll
    for (int o = 1; o < 64; o <<= 1) m = fmaxf(m, __shfl_xor(m, o));
    if ((tid & 63) == 0) rs[tid >> 6] = m;
  }
  __syncthreads();
  const float m = fmaxf(rs[0], rs[1]);
  const float e = (tid < t) ? __expf(s - m) : 0.f;
  if (tid < 128) {
    float sum = e;
    #pragma unroll
    for (int o = 1; o < 64; o <<= 1) sum += __shfl_xor(sum, o);
    if ((tid & 63) == 0) rs[2 + (tid >> 6)] = sum;
  }
  __syncthreads();
  if (tid < 128) al[tid] = e / (rs[2] + rs[3]);
  __syncthreads();
  const int ug = tid >> 6, dg = tid & 63;
  float acc[16];
  #pragma unroll
  for (int i = 0; i < 16; ++i) acc[i] = 0.f;
  const u16* gb = p.ghist + (size_t)b*DD + dg*16;
  for (int u0 = ug; u0 < t; u0 += 32) {
    bf16x8 g0[8], g1[8]; float av[8];
    #pragma unroll
    for (int i = 0; i < 8; ++i) {
      const int u = u0 + i*4;
      if (u < t) {
        g0[i] = *(const bf16x8*)(gb + (size_t)u*BB*DD);
        g1[i] = *(const bf16x8*)(gb + (size_t)u*BB*DD + 8);
        av[i] = al[u];
      } else {
        av[i] = 0.f;
        g0[i] = (bf16x8){0,0,0,0,0,0,0,0};
        g1[i] = (bf16x8){0,0,0,0,0,0,0,0};
      }
    }
    #pragma unroll
    for (int i = 0; i < 8; ++i)
      #pragma unroll
      for (int d = 0; d < 8; ++d) {
        acc[d]   += av[i] * b2f((u16)g0[i][d]);
        acc[8+d] += av[i] * b2f((u16)g1[i][d]);
      }
  }
  #pragma unroll
  for (int i = 0; i < 4; ++i)
    *(f32x4*)(part + ((size_t)(ug*64 + dg))*16 + i*4) =
      (f32x4){acc[i*4], acc[i*4+1], acc[i*4+2], acc[i*4+3]};
  __syncthreads();
  const int d = tid * 4;
  const int dgf = d >> 4, di = d & 15;
  f32x4 sum = {0,0,0,0};
  #pragma unroll
  for (int u2 = 0; u2 < 4; ++u2) sum += *(f32x4*)(part + ((size_t)(u2*64 + dgf))*16 + di);
  s16x4 o;
  #pragma unroll
  for (int q = 0; q < 4; ++q) o[q] = (short)f2b(sum[q]);
  *(s16x4*)(p.cb + (size_t)b*DD + d) = o;
}

// ---- 64x64-tile GEMM, 256 thr (2 K-halves x 2 N-halves), 4-deep prefetch; for GIPa ----
template<typename TA>
__device__ __attribute__((noinline)) void gemm_frag(
    const TA* __restrict__ A, const u16* __restrict__ W, int ldW,
    int k0, int n0, float* __restrict__ C, float* red) {
  const int tid = threadIdx.x;
  const int wv  = tid >> 6;
  const int kh  = wv >> 1;
  const int nh  = wv & 1;
  const int lane = tid & 63;
  const int l15 = lane & 15;
  const int l4  = lane >> 4;
  const TA*  Ab = A + (size_t)l15 * DD + kh * 512 + l4 * 8;
  const u16* Wb = W + (size_t)(n0 + nh*32 + l15) * ldW + k0 + kh * 512 + l4 * 8;

  f32x4 acc[4][2];
  #pragma unroll
  for (int i = 0; i < 4; ++i) { acc[i][0] = (f32x4){0,0,0,0}; acc[i][1] = (f32x4){0,0,0,0}; }

  bf16x8 af[4][4], wf[4][2];
  #pragma unroll
  for (int i = 0; i < 3; ++i) {
    const int ko = i * 32;
    #pragma unroll
    for (int bt = 0; bt < 4; ++bt) loadA(af[i][bt], Ab + (size_t)bt*16*DD + ko);
    wf[i][0] = *(const bf16x8*)(Wb + ko);
    wf[i][1] = *(const bf16x8*)(Wb + (size_t)16*ldW + ko);
  }
  #pragma unroll
  for (int kt = 0; kt < 16; ++kt) {
    const int cur = kt & 3;
    const int pft = kt + 3;
    if (pft < 16) {
      const int nb = pft & 3;
      const int ko = pft * 32;
      #pragma unroll
      for (int bt = 0; bt < 4; ++bt) loadA(af[nb][bt], Ab + (size_t)bt*16*DD + ko);
      wf[nb][0] = *(const bf16x8*)(Wb + ko);
      wf[nb][1] = *(const bf16x8*)(Wb + (size_t)16*ldW + ko);
    }
    #pragma unroll
    for (int bt = 0; bt < 4; ++bt) {
      acc[bt][0] = __builtin_amdgcn_mfma_f32_16x16x32_bf16(af[cur][bt], wf[cur][0], acc[bt][0], 0,0,0);
      acc[bt][1] = __builtin_amdgcn_mfma_f32_16x16x32_bf16(af[cur][bt], wf[cur][1], acc[bt][1], 0,0,0);
    }
  }
  if (kh == 1) {
    #pragma unroll
    for (int bt = 0; bt < 4; ++bt)
      #pragma unroll
      for (int nt = 0; nt < 2; ++nt)
        #pragma unroll
        for (int q = 0; q < 4; ++q)
          red[(bt*16 + l4*4 + q)*64 + nh*32 + nt*16 + l15] = acc[bt][nt][q];
  }
  __syncthreads();
  if (kh == 0) {
    #pragma unroll
    for (int bt = 0; bt < 4; ++bt)
      #pragma unroll
      for (int nt = 0; nt < 2; ++nt)
        #pragma unroll
        for (int q = 0; q < 4; ++q) {
          const int row = bt*16 + l4*4 + q;
          const int col = nh*32 + nt*16 + l15;
          C[(size_t)row*G3 + n0 + col] = acc[bt][nt][q] + red[row*64 + col];
        }
  }
}

// ---- DA: fusedG(64) | fusedE(64) | attn(64) = 192 blocks x 256 ----
__global__ void __launch_bounds__(256) k1_step(DPar p, int t) {
  __shared__ __align__(16) char lds[49152];
  const int blk = (int)blockIdx.x;
  if (blk < 64)        fusedG(p, t, blk, lds);
  else if (blk < 128)  { if (t) fusedE(p, t, blk-64, lds); }
  else                 { if (t) attn_run(p, t, blk-128, (float*)lds); }
}

// ---- DB: party(64: GIPb + GHP + combine) | GIPa(t+1)(48) = 112 blocks x 256 ----
__global__ void __launch_bounds__(256) k2_step(DPar p, int t) {
  __shared__ __align__(16) float L[12288];   // 48 KB
  const int tid = (int)threadIdx.x;
  const int blk = (int)blockIdx.x;
  if (blk < 64) {
    float* LI0 = L;          float* LI1 = L + 3072;
    float* LH0 = L + 6144;   float* LH1 = L + 9216;
    const int kq = tid >> 6;
    const int lane = tid & 63, l15 = lane & 15, l4 = lane >> 4;
    const int lofs = l4 * 8;
    const int j0 = blk * 16;
    const size_t r0 = (size_t)(j0 + l15);
    const u16* qsel = (t & 1) ? p.qsel1 : p.qsel0;
    f32x4 acc[4][3];
    zeroAcc(acc);
    { // GIPb: c_t against second K-half of A3
      const int kw = 1024 + kq*256;
      const u16* W0 = p.A3 + (r0       )*2048 + kw + lofs;
      const u16* W1 = p.A3 + (r0 + 1024)*2048 + kw + lofs;
      const u16* W2 = p.A3 + (r0 + 2048)*2048 + kw + lofs;
      gemm3<8>(p.cb + (size_t)l15*DD + kq*256 + lofs, DD, W0, W1, W2, acc);
    }
    if (kq == 1) parkAcc48(LI0, acc, l15, l4, false);
    if (kq == 3) parkAcc48(LI1, acc, l15, l4, false);
    __syncthreads();
    if (kq == 0) parkAcc48(LI0, acc, l15, l4, true);
    if (kq == 2) parkAcc48(LI1, acc, l15, l4, true);
    zeroAcc(acc);
    { // GHP: qsel_t @ Whh_p^T (A4, K=1024 quarters)
      const int kw = kq*256;
      const u16* W0 = p.A4 + (r0       )*1024 + kw + lofs;
      const u16* W1 = p.A4 + (r0 + 1024)*1024 + kw + lofs;
      const u16* W2 = p.A4 + (r0 + 2048)*1024 + kw + lofs;
      gemm3<8>(qsel + (size_t)l15*DD + kw + lofs, DD, W0, W1, W2, acc);
    }
    if (kq == 1) parkAcc48(LH0, acc, l15, l4, false);
    if (kq == 3) parkAcc48(LH1, acc, l15, l4, false);
    __syncthreads();
    if (kq == 0) parkAcc48(LH0, acc, l15, l4, true);
    if (kq == 2) parkAcc48(LH1, acc, l15, l4, true);
    __syncthreads();
    if (tid < 128) {
      const int b = tid >> 1, jjb = (tid & 1) * 8;
      const int spkc = p.spk[t*BB + b];
      const int spkn = (t+1 < TT) ? p.spk[(t+1)*BB + b] : spkc;
      float* prow = p.parties + (size_t)(b*2 + spkc)*DD;
      const float* orow = p.parties + (size_t)(b*2 + spkn)*DD;
      const float* Gia = ((t & 1) ? p.GIPa1 : p.GIPa0) + (size_t)b*G3;
      const float* i0 = LI0 + b*48; const float* i1 = LI1 + b*48;
      const float* h0 = LH0 + b*48; const float* h1 = LH1 + b*48;
      u16* qselw = ((t+1) & 1) ? p.qsel1 : p.qsel0;
      float qn8[8], qs8[8];
      #pragma unroll
      for (int i = 0; i < 8; ++i) {
        const int jj = jjb + i, j = j0 + jj;
        const float gi_r = Gia[j]      + i0[jj]    + i1[jj]    + p.bihp[j];
        const float gi_z = Gia[1024+j] + i0[16+jj] + i1[16+jj] + p.bihp[1024+j];
        const float gi_n = Gia[2048+j] + i0[32+jj] + i1[32+jj] + p.bihp[2048+j];
        const float gh_r = h0[jj]    + h1[jj]    + p.bhhp[j];
        const float gh_z = h0[16+jj] + h1[16+jj] + p.bhhp[1024+j];
        const float gh_n = h0[32+jj] + h1[32+jj] + p.bhhp[2048+j];
        const float r_ = sigm(gi_r + gh_r);
        const float z_ = sigm(gi_z + gh_z);
        const float n_ = tanh_(gi_n + r_*gh_n);
        const float h  = prow[j];
        const float qv = (1.f - z_)*n_ + z_*h;
        prow[j] = qv;
        qn8[i] = qv;
        qs8[i] = (spkn == spkc) ? qv : orow[j];
      }
      bf16x8 qn, qs;
      #pragma unroll
      for (int i = 0; i < 8; ++i) { qn[i] = (short)f2b(qn8[i]); qs[i] = (short)f2b(qs8[i]); }
      *(bf16x8*)(p.qnewb + (size_t)b*DD + j0 + jjb) = qn;
      *(bf16x8*)(qselw   + (size_t)b*DD + j0 + jjb) = qs;
    }
  } else {
    if (t + 1 < TT) {
      float* GIPn = ((t + 1) & 1) ? p.GIPa1 : p.GIPa0;
      gemm_frag(p.feat + (size_t)(t+1)*BB*DD, p.A3, 2048, 0, (blk-64)*64, GIPn, L);
    }
  }
}

// ---- prologue: GIPa(0) ----
__global__ void __launch_bounds__(256) kPre(DPar p) {
  __shared__ __align__(16) float red[4096];
  gemm_frag(p.feat, p.A3, 2048, 0, (int)blockIdx.x*64, p.GIPa0, red);
}

// ---- epilogue: emotion step 127 ----
__global__ void __launch_bounds__(256) kEpi(DPar p) {
  __shared__ __align__(16) char lds[49152];
  fusedE(p, TT, (int)blockIdx.x, lds);
}

// ---- setup: weight fp32 -> bf16 cast + state zero + speaker idx (every launch) ----
__global__ void setupK(const float* __restrict__ Wg, const float* __restrict__ Whg,
                       const float* __restrict__ Wp, const float* __restrict__ Whp,
                       const float* __restrict__ We, const float* __restrict__ Whe,
                       u16* A1, u16* A2, u16* A3, u16* A4, u16* A5, u16* A6,
                       float* parties, float* gf, float* ef,
                       u16* cb, u16* qsel0, u16* qsel1, u16* qnewb, u16* eb0, u16* eb1,
                       const float* spkOH, int* spk) {
  long gid = (long)blockIdx.x*256 + threadIdx.x;
  if (gid < BB*2*DD) parties[gid] = 0.f;
  if (gid < BB*DD) {
    gf[gid] = 0.f; ef[gid] = 0.f;
    cb[gid] = 0; qsel0[gid] = 0; qsel1[gid] = 0; qnewb[gid] = 0; eb0[gid] = 0; eb1[gid] = 0;
  }
  if (gid < TT*BB) spk[gid] = (spkOH[(size_t)gid*2 + 1] > 0.5f) ? 1 : 0;
  const long n1 = (long)G3*2048/4, n2 = (long)G3*1024/4;
  const long tot = 2*n1 + 4*n2;
  const long stride = (long)gridDim.x*256;
  for (long i = gid; i < tot; i += stride) {
    const float* src; u16* dst; long o = i;
    if (o < n1) { src = Wg;  dst = A1; }
    else { o -= n1;
      if (o < n2) { src = Whg; dst = A2; }
      else { o -= n2;
        if (o < n1) { src = Wp; dst = A3; }
        else { o -= n1;
          if (o < n2) { src = Whp; dst = A4; }
          else { o -= n2;
            if (o < n2) { src = We; dst = A5; }
            else { o -= n2; src = Whe; dst = A6; }
          }
        }
      }
    }
    f32x4 v = *(const f32x4*)(src + o*4);
    s16x4 w;
    w[0] = (short)f2b(v[0]); w[1] = (short)f2b(v[1]);
    w[2] = (short)f2b(v[2]); w[3] = (short)f2b(v[3]);
    *(s16x4*)(dst + o*4) = w;
  }
}

extern "C" void kernel_launch(void* const* d_in, const int* in_sizes, int n_in,
                              void* d_out, int out_size, void* d_ws, size_t ws_size,
                              hipStream_t stream) {
  const float* feat  = (const float*)d_in[0];
  const float* spkOH = (const float*)d_in[1];
  const float* Wih_g = (const float*)d_in[2];
  const float* Whh_g = (const float*)d_in[3];
  const float* bih_g = (const float*)d_in[4];
  const float* bhh_g = (const float*)d_in[5];
  const float* Wih_p = (const float*)d_in[6];
  const float* Whh_p = (const float*)d_in[7];
  const float* bih_p = (const float*)d_in[8];
  const float* bhh_p = (const float*)d_in[9];
  const float* Wih_e = (const float*)d_in[10];
  const float* Whh_e = (const float*)d_in[11];
  const float* bih_e = (const float*)d_in[12];
  const float* bhh_e = (const float*)d_in[13];
  const float* watt  = (const float*)d_in[14];

  char* w = (char*)d_ws;
  auto alloc = [&](size_t bytes) -> char* {
    char* r = w; w += (bytes + 255) & ~(size_t)255; return r;
  };
  u16* ghist = (u16*)alloc((size_t)TT*BB*DD*2);
  float* scoresP = (float*)alloc((size_t)TT*64*BB*4);
  u16* cb    = (u16*)alloc((size_t)BB*DD*2);
  u16* qsel0 = (u16*)alloc((size_t)BB*DD*2);
  u16* qsel1 = (u16*)alloc((size_t)BB*DD*2);
  u16* qnewb = (u16*)alloc((size_t)BB*DD*2);
  u16* eb0   = (u16*)alloc((size_t)BB*DD*2);
  u16* eb1   = (u16*)alloc((size_t)BB*DD*2);
  float* parties = (float*)alloc((size_t)BB*2*DD*4);
  float* gf  = (float*)alloc((size_t)BB*DD*4);
  float* ef  = (float*)alloc((size_t)BB*DD*4);
  float* GIPa0 = (float*)alloc((size_t)BB*G3*4);
  float* GIPa1 = (float*)alloc((size_t)BB*G3*4);
  int* spk    = (int*)alloc((size_t)TT*BB*4);
  u16* A1 = (u16*)alloc((size_t)G3*2048*2);
  u16* A2 = (u16*)alloc((size_t)G3*1024*2);
  u16* A3 = (u16*)alloc((size_t)G3*2048*2);
  u16* A4 = (u16*)alloc((size_t)G3*1024*2);
  u16* A5 = (u16*)alloc((size_t)G3*1024*2);
  u16* A6 = (u16*)alloc((size_t)G3*1024*2);
  const size_t need = (size_t)(w - (char*)d_ws);   // ~72 MB < proven 75.5 MB bound
  if (ws_size < need) return;   // fail validation visibly rather than fault

  hipLaunchKernelGGL(setupK, dim3(2048), dim3(256), 0, stream,
                     Wih_g, Whh_g, Wih_p, Whh_p, Wih_e, Whh_e,
                     A1, A2, A3, A4, A5, A6,
                     parties, gf, ef, cb, qsel0, qsel1, qnewb, eb0, eb1, spkOH, spk);

  DPar p;
  p.A1 = A1; p.A2 = A2; p.A3 = A3; p.A4 = A4; p.A5 = A5; p.A6 = A6;
  p.feat = feat;
  p.ghist = ghist; p.cb = cb; p.qsel0 = qsel0; p.qsel1 = qsel1; p.qnewb = qnewb;
  p.eb0 = eb0; p.eb1 = eb1;
  p.scoresP = scoresP; p.parties = parties; p.gf = gf; p.ef = ef;
  p.GIPa0 = GIPa0; p.GIPa1 = GIPa1;
  p.bihg = bih_g; p.bhhg = bhh_g; p.bihp = bih_p; p.bhhp = bhh_p;
  p.bihe = bih_e; p.bhhe = bhh_e; p.watt = watt;
  p.spk = spk; p.out = (float*)d_out;

  hipLaunchKernelGGL(kPre, dim3(48), dim3(256), 0, stream, p);
  for (int t = 0; t < TT; ++t) {
    hipLaunchKernelGGL(k1_step, dim3(192), dim3(256), 0, stream, p, t);
    hipLaunchKernelGGL(k2_step, dim3(112), dim3(256), 0, stream, p, t);
  }
  hipLaunchKernelGGL(kEpi, dim3(64), dim3(256), 0, stream, p);
}

// Round 12
// 5687.156 us; speedup vs baseline: 1.8049x; 1.8049x over previous
//
#include <hip/hip_runtime.h>
#include <stdint.h>

#define TT 128
#define BB 64
#define DD 1024
#define G3 3072

typedef unsigned short u16;
typedef unsigned int u32;
typedef __attribute__((ext_vector_type(8))) short bf16x8;
typedef __attribute__((ext_vector_type(4))) short s16x4;
typedef __attribute__((ext_vector_type(4))) float f32x4;

__device__ __forceinline__ float b2f(u16 h){ u32 u = ((u32)h)<<16; float f; __builtin_memcpy(&f,&u,4); return f; }
__device__ __forceinline__ u16 f2b(float f){ u32 u; __builtin_memcpy(&u,&f,4); u = (u + 0x7fffu + ((u>>16)&1u))>>16; return (u16)u; }
__device__ __forceinline__ float sigm(float x){ return 1.f/(1.f+__expf(-x)); }
__device__ __forceinline__ float tanh_(float x){
  if (x > 10.f) return 1.f;
  if (x < -10.f) return -1.f;
  float e = __expf(2.f*x); return (e-1.f)/(e+1.f);
}

struct DPar {
  const u16 *A1,*A2,*A3,*A4,*A5,*A6;   // bf16 weights
  const float* feat;
  u16 *ghist,*qsel0,*qsel1,*qnew0,*qnew1,*eb0,*eb1;
  float *scoresP;                       // [TT][64][BB] per-block score partials
  float *parties,*gf,*ef,*GIPa0,*GIPa1;
  float *N0,*N1,*m0,*m1,*Z0,*Z1;        // online-softmax state (parity)
  const float *bihg,*bhhg,*bihp,*bhhp,*bihe,*bhhe,*watt;
  const int* spk;
  float* out;
};

// ---- A-fragment loaders (bf16 direct; fp32 converted in-flight) ----
__device__ __forceinline__ void loadA(bf16x8& d, const u16* p){ d = *(const bf16x8*)p; }
__device__ __forceinline__ void loadA(bf16x8& d, const float* p){
  f32x4 lo = *(const f32x4*)p;
  f32x4 hi = *(const f32x4*)(p + 4);
  #pragma unroll
  for (int i = 0; i < 4; ++i) { d[i] = (short)f2b(lo[i]); d[i+4] = (short)f2b(hi[i]); }
}

__device__ __forceinline__ void zeroAcc(f32x4 (&a)[4][3]) {
  #pragma unroll
  for (int i = 0; i < 4; ++i) {
    a[i][0] = (f32x4){0,0,0,0}; a[i][1] = (f32x4){0,0,0,0}; a[i][2] = (f32x4){0,0,0,0};
  }
}

// ---- per-wave GEMM: 4 batch-tiles x 3 gate-tiles, NK k-tiles, 4-deep prefetch ----
template<int NK, typename TA>
__device__ __forceinline__ void gemm3(const TA* __restrict__ Ab, int ldA,
    const u16* __restrict__ W0, const u16* __restrict__ W1, const u16* __restrict__ W2,
    f32x4 (&acc)[4][3]) {
  bf16x8 af[4][4], wf[4][3];
  #pragma unroll
  for (int i = 0; i < 3; ++i) {
    const int ko = i * 32;
    #pragma unroll
    for (int bt = 0; bt < 4; ++bt) loadA(af[i][bt], Ab + (size_t)bt*16*ldA + ko);
    wf[i][0] = *(const bf16x8*)(W0 + ko);
    wf[i][1] = *(const bf16x8*)(W1 + ko);
    wf[i][2] = *(const bf16x8*)(W2 + ko);
  }
  #pragma unroll
  for (int kt = 0; kt < NK; ++kt) {
    const int cur = kt & 3;
    const int pft = kt + 3;
    if (pft < NK) {
      const int nb = pft & 3;
      const int ko = pft * 32;
      #pragma unroll
      for (int bt = 0; bt < 4; ++bt) loadA(af[nb][bt], Ab + (size_t)bt*16*ldA + ko);
      wf[nb][0] = *(const bf16x8*)(W0 + ko);
      wf[nb][1] = *(const bf16x8*)(W1 + ko);
      wf[nb][2] = *(const bf16x8*)(W2 + ko);
    }
    #pragma unroll
    for (int bt = 0; bt < 4; ++bt) {
      acc[bt][0] = __builtin_amdgcn_mfma_f32_16x16x32_bf16(af[cur][bt], wf[cur][0], acc[bt][0], 0,0,0);
      acc[bt][1] = __builtin_amdgcn_mfma_f32_16x16x32_bf16(af[cur][bt], wf[cur][1], acc[bt][1], 0,0,0);
      acc[bt][2] = __builtin_amdgcn_mfma_f32_16x16x32_bf16(af[cur][bt], wf[cur][2], acc[bt][2], 0,0,0);
    }
  }
}

// ---- park (write) or accumulate (add) a wave's acc into LDS [64][48] ----
__device__ __forceinline__ void parkAcc48(float* L, f32x4 (&acc)[4][3], int l15, int l4, bool add) {
  #pragma unroll
  for (int bt = 0; bt < 4; ++bt)
    #pragma unroll
    for (int ci = 0; ci < 3; ++ci) {
      const int col = ci*16 + l15;
      #pragma unroll
      for (int q = 0; q < 4; ++q) {
        float* s = L + (bt*16 + l4*4 + q)*48 + col;
        if (add) *s += acc[bt][ci][q]; else *s = acc[bt][ci][q];
      }
    }
}

// ---- fused global GRU (64 blocks, 16 cols): 4-way-K GEMMs + combine ----
__device__ void fusedG(const DPar& p, int t, int bj, char* ldsraw) {
  float* LI0 = (float*)ldsraw;
  float* LI1 = LI0 + 3072;
  float* LH0 = LI1 + 3072;
  float* LH1 = LH0 + 3072;
  const int tid = (int)threadIdx.x;
  const int kq = tid >> 6;
  const int lane = tid & 63, l15 = lane & 15, l4 = lane >> 4;
  const int lofs = l4 * 8;
  const int j0 = bj * 16;
  const size_t r0 = (size_t)(j0 + l15);
  const u16* qsel = (t & 1) ? p.qsel1 : p.qsel0;
  f32x4 acc[4][3];
  zeroAcc(acc);
  { // i-part: X = [feat | qsel], K=2048 quarters of 512
    const int kw = (kq < 2) ? kq*512 : 1024 + (kq - 2)*512;
    const u16* W0 = p.A1 + (r0       )*2048 + kw + lofs;
    const u16* W1 = p.A1 + (r0 + 1024)*2048 + kw + lofs;
    const u16* W2 = p.A1 + (r0 + 2048)*2048 + kw + lofs;
    if (kq < 2) gemm3<16>(p.feat + (size_t)t*BB*DD + (size_t)l15*DD + kq*512 + lofs, DD, W0, W1, W2, acc);
    else        gemm3<16>(qsel + (size_t)l15*DD + (kq-2)*512 + lofs, DD, W0, W1, W2, acc);
  }
  if (kq == 1) parkAcc48(LI0, acc, l15, l4, false);
  if (kq == 3) parkAcc48(LI1, acc, l15, l4, false);
  __syncthreads();
  if (kq == 0) parkAcc48(LI0, acc, l15, l4, true);
  if (kq == 2) parkAcc48(LI1, acc, l15, l4, true);
  zeroAcc(acc);
  if (t) { // h-part: g_{t-1}, K=1024 quarters of 256
    const int kw = kq*256;
    const u16* W0 = p.A2 + (r0       )*1024 + kw + lofs;
    const u16* W1 = p.A2 + (r0 + 1024)*1024 + kw + lofs;
    const u16* W2 = p.A2 + (r0 + 2048)*1024 + kw + lofs;
    gemm3<8>(p.ghist + (size_t)(t-1)*BB*DD + (size_t)l15*DD + kw + lofs, DD, W0, W1, W2, acc);
  }
  if (kq == 1) parkAcc48(LH0, acc, l15, l4, false);
  if (kq == 3) parkAcc48(LH1, acc, l15, l4, false);
  __syncthreads();
  if (kq == 0) parkAcc48(LH0, acc, l15, l4, true);
  if (kq == 2) parkAcc48(LH1, acc, l15, l4, true);
  __syncthreads();
  if (tid < 128) {
    const int b = tid >> 1, jjb = (tid & 1) * 8;
    const float* i0 = LI0 + b*48; const float* i1 = LI1 + b*48;
    const float* h0 = LH0 + b*48; const float* h1 = LH1 + b*48;
    float gv8[8]; float scp = 0.f;
    #pragma unroll
    for (int i = 0; i < 8; ++i) {
      const int jj = jjb + i, j = j0 + jj;
      const float ir = i0[jj]    + i1[jj]    + p.bihg[j];
      const float iz = i0[16+jj] + i1[16+jj] + p.bihg[1024+j];
      const float in_= i0[32+jj] + i1[32+jj] + p.bihg[2048+j];
      const float hr = h0[jj]    + h1[jj]    + p.bhhg[j];
      const float hz = h0[16+jj] + h1[16+jj] + p.bhhg[1024+j];
      const float hn = h0[32+jj] + h1[32+jj] + p.bhhg[2048+j];
      const float r_ = sigm(ir + hr);
      const float z_ = sigm(iz + hz);
      const float n_ = tanh_(in_ + r_*hn);
      const float gp = p.gf[(size_t)b*DD + j];
      const float gv = (1.f - z_)*n_ + z_*gp;
      p.gf[(size_t)b*DD + j] = gv;
      gv8[i] = gv;
      scp += gv * p.watt[j];
    }
    bf16x8 hh;
    #pragma unroll
    for (int i = 0; i < 8; ++i) hh[i] = (short)f2b(gv8[i]);
    *(bf16x8*)(p.ghist + (size_t)t*BB*DD + (size_t)b*DD + j0 + jjb) = hh;
    scp += __shfl_xor(scp, 1);
    if ((tid & 1) == 0) p.scoresP[(size_t)t*64*BB + (size_t)bj*BB + b] = scp;
  }
}

// ---- fused emotion GRU (64 blocks, 16 cols): emotion step td = t-1 ----
__device__ void fusedE(const DPar& p, int t, int bj, char* ldsraw) {
  const int td = t - 1;
  float* LI0 = (float*)ldsraw;
  float* LI1 = LI0 + 3072;
  float* LH0 = LI1 + 3072;
  float* LH1 = LH0 + 3072;
  const int tid = (int)threadIdx.x;
  const int kq = tid >> 6;
  const int lane = tid & 63, l15 = lane & 15, l4 = lane >> 4;
  const int lofs = l4 * 8;
  const int j0 = bj * 16;
  const size_t r0 = (size_t)(j0 + l15);
  const u16* qn = ((t-1) & 1) ? p.qnew1 : p.qnew0;   // qnew_{t-1}
  f32x4 acc[4][3];
  zeroAcc(acc);
  { // i-part: qnew_{td}, K=1024 quarters
    const int kw = kq*256;
    const u16* W0 = p.A5 + (r0       )*1024 + kw + lofs;
    const u16* W1 = p.A5 + (r0 + 1024)*1024 + kw + lofs;
    const u16* W2 = p.A5 + (r0 + 2048)*1024 + kw + lofs;
    gemm3<8>(qn + (size_t)l15*DD + kw + lofs, DD, W0, W1, W2, acc);
  }
  if (kq == 1) parkAcc48(LI0, acc, l15, l4, false);
  if (kq == 3) parkAcc48(LI1, acc, l15, l4, false);
  __syncthreads();
  if (kq == 0) parkAcc48(LI0, acc, l15, l4, true);
  if (kq == 2) parkAcc48(LI1, acc, l15, l4, true);
  zeroAcc(acc);
  if (td > 0) { // h-part: e_{td-1}
    const u16* ebr = (t & 1) ? p.eb1 : p.eb0;
    const int kw = kq*256;
    const u16* W0 = p.A6 + (r0       )*1024 + kw + lofs;
    const u16* W1 = p.A6 + (r0 + 1024)*1024 + kw + lofs;
    const u16* W2 = p.A6 + (r0 + 2048)*1024 + kw + lofs;
    gemm3<8>(ebr + (size_t)l15*DD + kw + lofs, DD, W0, W1, W2, acc);
  }
  if (kq == 1) parkAcc48(LH0, acc, l15, l4, false);
  if (kq == 3) parkAcc48(LH1, acc, l15, l4, false);
  __syncthreads();
  if (kq == 0) parkAcc48(LH0, acc, l15, l4, true);
  if (kq == 2) parkAcc48(LH1, acc, l15, l4, true);
  __syncthreads();
  if (tid < 128) {
    const int b = tid >> 1, jjb = (tid & 1) * 8;
    const float* i0 = LI0 + b*48; const float* i1 = LI1 + b*48;
    const float* h0 = LH0 + b*48; const float* h1 = LH1 + b*48;
    float ev8[8];
    #pragma unroll
    for (int i = 0; i < 8; ++i) {
      const int jj = jjb + i, j = j0 + jj;
      const float ir = i0[jj]    + i1[jj]    + p.bihe[j];
      const float iz = i0[16+jj] + i1[16+jj] + p.bihe[1024+j];
      const float in_= i0[32+jj] + i1[32+jj] + p.bihe[2048+j];
      const float hr = h0[jj]    + h1[jj]    + p.bhhe[j];
      const float hz = h0[16+jj] + h1[16+jj] + p.bhhe[1024+j];
      const float hn = h0[32+jj] + h1[32+jj] + p.bhhe[2048+j];
      const float r_ = sigm(ir + hr);
      const float z_ = sigm(iz + hz);
      const float n_ = tanh_(in_ + r_*hn);
      const float ep = p.ef[(size_t)b*DD + j];
      const float ev = (1.f - z_)*n_ + z_*ep;
      p.ef[(size_t)b*DD + j] = ev;
      ev8[i] = ev;
    }
    float* orow = p.out + (size_t)td*BB*DD + (size_t)b*DD + j0 + jjb;
    *(f32x4*)orow       = (f32x4){ev8[0], ev8[1], ev8[2], ev8[3]};
    *(f32x4*)(orow + 4) = (f32x4){ev8[4], ev8[5], ev8[6], ev8[7]};
    u16* ebw = ((t-1) & 1) ? p.eb1 : p.eb0;
    bf16x8 ee;
    #pragma unroll
    for (int i = 0; i < 8; ++i) ee[i] = (short)f2b(ev8[i]);
    *(bf16x8*)(ebw + (size_t)b*DD + j0 + jjb) = ee;
  }
}

// ---- fused party GRU + inline online-softmax attention (64 blocks, 16 cols) ----
// GIPb_t[slice] = (N_{t-1}[slice]*e^{m_old-m_new} + e^{s_{t-1}-m_new} * (g_{t-1}@W)[slice]) / Z_new
__device__ void fusedP(const DPar& p, int t, int bj, char* ldsraw) {
  float* LI0 = (float*)ldsraw;     // GW = ghist(t-1) @ Wp2 slice
  float* LI1 = LI0 + 3072;
  float* LH0 = LI1 + 3072;         // GHP = qsel_t @ Whh_p slice
  float* LH1 = LH0 + 3072;
  const int tid = (int)threadIdx.x;
  const int kq = tid >> 6;
  const int lane = tid & 63, l15 = lane & 15, l4 = lane >> 4;
  const int lofs = l4 * 8;
  const int j0 = bj * 16;
  const size_t r0 = (size_t)(j0 + l15);
  const u16* qsel = (t & 1) ? p.qsel1 : p.qsel0;
  f32x4 acc[4][3];
  zeroAcc(acc);
  if (t) { // GW: ghist(t-1) against second K-half of A3
    const int kw = 1024 + kq*256;
    const u16* W0 = p.A3 + (r0       )*2048 + kw + lofs;
    const u16* W1 = p.A3 + (r0 + 1024)*2048 + kw + lofs;
    const u16* W2 = p.A3 + (r0 + 2048)*2048 + kw + lofs;
    gemm3<8>(p.ghist + (size_t)(t-1)*BB*DD + (size_t)l15*DD + kq*256 + lofs, DD, W0, W1, W2, acc);
  }
  if (kq == 1) parkAcc48(LI0, acc, l15, l4, false);
  if (kq == 3) parkAcc48(LI1, acc, l15, l4, false);
  __syncthreads();
  if (kq == 0) parkAcc48(LI0, acc, l15, l4, true);
  if (kq == 2) parkAcc48(LI1, acc, l15, l4, true);
  zeroAcc(acc);
  { // GHP: qsel_t @ Whh_p^T (A4, K=1024 quarters)
    const int kw = kq*256;
    const u16* W0 = p.A4 + (r0       )*1024 + kw + lofs;
    const u16* W1 = p.A4 + (r0 + 1024)*1024 + kw + lofs;
    const u16* W2 = p.A4 + (r0 + 2048)*1024 + kw + lofs;
    gemm3<8>(qsel + (size_t)l15*DD + kw + lofs, DD, W0, W1, W2, acc);
  }
  if (kq == 1) parkAcc48(LH0, acc, l15, l4, false);
  if (kq == 3) parkAcc48(LH1, acc, l15, l4, false);
  __syncthreads();
  if (kq == 0) parkAcc48(LH0, acc, l15, l4, true);
  if (kq == 2) parkAcc48(LH1, acc, l15, l4, true);
  __syncthreads();
  if (tid < 128) {
    const int b = tid >> 1, jjb = (tid & 1) * 8;
    // online-softmax scalar update for batch b (redundant per thread; deterministic)
    float mN = -1e30f, Zn = 0.f, scl = 0.f, wn = 0.f, invZ = 0.f;
    if (t > 0) {
      const float* sp = p.scoresP + (size_t)(t-1)*64*BB + b;
      float s = 0.f;
      #pragma unroll
      for (int pp = 0; pp < 64; ++pp) s += sp[pp*BB];
      const float mo = ((t-1) & 1 ? p.m1 : p.m0)[b];
      const float Zo = ((t-1) & 1 ? p.Z1 : p.Z0)[b];
      mN  = fmaxf(mo, s);
      scl = __expf(mo - mN);
      wn  = __expf(s - mN);
      Zn  = Zo*scl + wn;
      invZ = 1.f / Zn;
    }
    float* Nw = (t & 1) ? p.N1 : p.N0;
    const float* Nr = (t & 1) ? p.N0 : p.N1;
    const int spkc = p.spk[t*BB + b];
    const int spkn = (t+1 < TT) ? p.spk[(t+1)*BB + b] : spkc;
    float* prow = p.parties + (size_t)(b*2 + spkc)*DD;
    const float* orow = p.parties + (size_t)(b*2 + spkn)*DD;
    const float* Gia = ((t & 1) ? p.GIPa1 : p.GIPa0) + (size_t)b*G3;
    const float* i0 = LI0 + b*48; const float* i1 = LI1 + b*48;
    const float* h0 = LH0 + b*48; const float* h1 = LH1 + b*48;
    u16* qselw = ((t+1) & 1) ? p.qsel1 : p.qsel0;
    u16* qneww = (t & 1) ? p.qnew1 : p.qnew0;
    float qn8[8], qs8[8];
    #pragma unroll
    for (int i = 0; i < 8; ++i) {
      const int jj = jjb + i, j = j0 + jj;
      float gipb[3];
      #pragma unroll
      for (int g = 0; g < 3; ++g) {
        const size_t col = (size_t)g*1024 + j;
        const float GW = i0[g*16+jj] + i1[g*16+jj];
        float Nn = 0.f;
        if (t > 0) Nn = Nr[(size_t)b*G3 + col]*scl + wn*GW;
        Nw[(size_t)b*G3 + col] = Nn;
        gipb[g] = Nn * invZ;
      }
      const float gi_r = Gia[j]      + gipb[0] + p.bihp[j];
      const float gi_z = Gia[1024+j] + gipb[1] + p.bihp[1024+j];
      const float gi_n = Gia[2048+j] + gipb[2] + p.bihp[2048+j];
      const float gh_r = h0[jj]    + h1[jj]    + p.bhhp[j];
      const float gh_z = h0[16+jj] + h1[16+jj] + p.bhhp[1024+j];
      const float gh_n = h0[32+jj] + h1[32+jj] + p.bhhp[2048+j];
      const float r_ = sigm(gi_r + gh_r);
      const float z_ = sigm(gi_z + gh_z);
      const float n_ = tanh_(gi_n + r_*gh_n);
      const float h  = prow[j];
      const float qv = (1.f - z_)*n_ + z_*h;
      prow[j] = qv;
      qn8[i] = qv;
      qs8[i] = (spkn == spkc) ? qv : orow[j];
    }
    if (bj == 0 && (tid & 1) == 0) {
      ((t & 1) ? p.m1 : p.m0)[b] = mN;
      ((t & 1) ? p.Z1 : p.Z0)[b] = Zn;
    }
    bf16x8 qn, qs;
    #pragma unroll
    for (int i = 0; i < 8; ++i) { qn[i] = (short)f2b(qn8[i]); qs[i] = (short)f2b(qs8[i]); }
    *(bf16x8*)(qneww + (size_t)b*DD + j0 + jjb) = qn;
    *(bf16x8*)(qselw + (size_t)b*DD + j0 + jjb) = qs;
  }
}

// ---- 64x64-tile GEMM, 256 thr (2 K-halves x 2 N-halves), 4-deep prefetch; for GIPa ----
template<typename TA>
__device__ __attribute__((noinline)) void gemm_frag(
    const TA* __restrict__ A, const u16* __restrict__ W, int ldW,
    int k0, int n0, float* __restrict__ C, float* red) {
  const int tid = threadIdx.x;
  const int wv  = tid >> 6;
  const int kh  = wv >> 1;
  const int nh  = wv & 1;
  const int lane = tid & 63;
  const int l15 = lane & 15;
  const int l4  = lane >> 4;
  const TA*  Ab = A + (size_t)l15 * DD + kh * 512 + l4 * 8;
  const u16* Wb = W + (size_t)(n0 + nh*32 + l15) * ldW + k0 + kh * 512 + l4 * 8;

  f32x4 acc[4][2];
  #pragma unroll
  for (int i = 0; i < 4; ++i) { acc[i][0] = (f32x4){0,0,0,0}; acc[i][1] = (f32x4){0,0,0,0}; }

  bf16x8 af[4][4], wf[4][2];
  #pragma unroll
  for (int i = 0; i < 3; ++i) {
    const int ko = i * 32;
    #pragma unroll
    for (int bt = 0; bt < 4; ++bt) loadA(af[i][bt], Ab + (size_t)bt*16*DD + ko);
    wf[i][0] = *(const bf16x8*)(Wb + ko);
    wf[i][1] = *(const bf16x8*)(Wb + (size_t)16*ldW + ko);
  }
  #pragma unroll
  for (int kt = 0; kt < 16; ++kt) {
    const int cur = kt & 3;
    const int pft = kt + 3;
    if (pft < 16) {
      const int nb = pft & 3;
      const int ko = pft * 32;
      #pragma unroll
      for (int bt = 0; bt < 4; ++bt) loadA(af[nb][bt], Ab + (size_t)bt*16*DD + ko);
      wf[nb][0] = *(const bf16x8*)(Wb + ko);
      wf[nb][1] = *(const bf16x8*)(Wb + (size_t)16*ldW + ko);
    }
    #pragma unroll
    for (int bt = 0; bt < 4; ++bt) {
      acc[bt][0] = __builtin_amdgcn_mfma_f32_16x16x32_bf16(af[cur][bt], wf[cur][0], acc[bt][0], 0,0,0);
      acc[bt][1] = __builtin_amdgcn_mfma_f32_16x16x32_bf16(af[cur][bt], wf[cur][1], acc[bt][1], 0,0,0);
    }
  }
  if (kh == 1) {
    #pragma unroll
    for (int bt = 0; bt < 4; ++bt)
      #pragma unroll
      for (int nt = 0; nt < 2; ++nt)
        #pragma unroll
        for (int q = 0; q < 4; ++q)
          red[(bt*16 + l4*4 + q)*64 + nh*32 + nt*16 + l15] = acc[bt][nt][q];
  }
  __syncthreads();
  if (kh == 0) {
    #pragma unroll
    for (int bt = 0; bt < 4; ++bt)
      #pragma unroll
      for (int nt = 0; nt < 2; ++nt)
        #pragma unroll
        for (int q = 0; q < 4; ++q) {
          const int row = bt*16 + l4*4 + q;
          const int col = nh*32 + nt*16 + l15;
          C[(size_t)row*G3 + n0 + col] = acc[bt][nt][q] + red[row*64 + col];
        }
  }
}

// ---- DA (one per step): fusedG(64) | fusedE(64) | fusedP(64) | GIPa(t+1)(48) = 240 ----
__global__ void __launch_bounds__(256) k_step(DPar p, int t) {
  __shared__ __align__(16) char lds[49152];
  const int blk = (int)blockIdx.x;
  if (blk < 64)        fusedG(p, t, blk, lds);
  else if (blk < 128)  { if (t) fusedE(p, t, blk-64, lds); }
  else if (blk < 192)  fusedP(p, t, blk-128, lds);
  else                 { if (t + 1 < TT)
                           gemm_frag(p.feat + (size_t)(t+1)*BB*DD, p.A3, 2048, 0, (blk-192)*64,
                                     ((t+1)&1) ? p.GIPa1 : p.GIPa0, (float*)lds); }
}

// ---- prologue: GIPa(0) ----
__global__ void __launch_bounds__(256) kPre(DPar p) {
  __shared__ __align__(16) float red[4096];
  gemm_frag(p.feat, p.A3, 2048, 0, (int)blockIdx.x*64, p.GIPa0, red);
}

// ---- epilogue: emotion step 127 ----
__global__ void __launch_bounds__(256) kEpi(DPar p) {
  __shared__ __align__(16) char lds[49152];
  fusedE(p, TT, (int)blockIdx.x, lds);
}

// ---- setup: weight fp32 -> bf16 cast + state zero + speaker idx (every launch) ----
__global__ void setupK(const float* __restrict__ Wg, const float* __restrict__ Whg,
                       const float* __restrict__ Wp, const float* __restrict__ Whp,
                       const float* __restrict__ We, const float* __restrict__ Whe,
                       u16* A1, u16* A2, u16* A3, u16* A4, u16* A5, u16* A6,
                       float* parties, float* gf, float* ef,
                       u16* qsel0, u16* qsel1, u16* qnew0, u16* qnew1, u16* eb0, u16* eb1,
                       const float* spkOH, int* spk) {
  long gid = (long)blockIdx.x*256 + threadIdx.x;
  if (gid < BB*2*DD) parties[gid] = 0.f;
  if (gid < BB*DD) {
    gf[gid] = 0.f; ef[gid] = 0.f;
    qsel0[gid] = 0; qsel1[gid] = 0; qnew0[gid] = 0; qnew1[gid] = 0; eb0[gid] = 0; eb1[gid] = 0;
  }
  if (gid < TT*BB) spk[gid] = (spkOH[(size_t)gid*2 + 1] > 0.5f) ? 1 : 0;
  const long n1 = (long)G3*2048/4, n2 = (long)G3*1024/4;
  const long tot = 2*n1 + 4*n2;
  const long stride = (long)gridDim.x*256;
  for (long i = gid; i < tot; i += stride) {
    const float* src; u16* dst; long o = i;
    if (o < n1) { src = Wg;  dst = A1; }
    else { o -= n1;
      if (o < n2) { src = Whg; dst = A2; }
      else { o -= n2;
        if (o < n1) { src = Wp; dst = A3; }
        else { o -= n1;
          if (o < n2) { src = Whp; dst = A4; }
          else { o -= n2;
            if (o < n2) { src = We; dst = A5; }
            else { o -= n2; src = Whe; dst = A6; }
          }
        }
      }
    }
    f32x4 v = *(const f32x4*)(src + o*4);
    s16x4 w;
    w[0] = (short)f2b(v[0]); w[1] = (short)f2b(v[1]);
    w[2] = (short)f2b(v[2]); w[3] = (short)f2b(v[3]);
    *(s16x4*)(dst + o*4) = w;
  }
}

extern "C" void kernel_launch(void* const* d_in, const int* in_sizes, int n_in,
                              void* d_out, int out_size, void* d_ws, size_t ws_size,
                              hipStream_t stream) {
  const float* feat  = (const float*)d_in[0];
  const float* spkOH = (const float*)d_in[1];
  const float* Wih_g = (const float*)d_in[2];
  const float* Whh_g = (const float*)d_in[3];
  const float* bih_g = (const float*)d_in[4];
  const float* bhh_g = (const float*)d_in[5];
  const float* Wih_p = (const float*)d_in[6];
  const float* Whh_p = (const float*)d_in[7];
  const float* bih_p = (const float*)d_in[8];
  const float* bhh_p = (const float*)d_in[9];
  const float* Wih_e = (const float*)d_in[10];
  const float* Whh_e = (const float*)d_in[11];
  const float* bih_e = (const float*)d_in[12];
  const float* bhh_e = (const float*)d_in[13];
  const float* watt  = (const float*)d_in[14];

  char* w = (char*)d_ws;
  auto alloc = [&](size_t bytes) -> char* {
    char* r = w; w += (bytes + 255) & ~(size_t)255; return r;
  };
  u16* ghist = (u16*)alloc((size_t)TT*BB*DD*2);
  float* scoresP = (float*)alloc((size_t)TT*64*BB*4);
  u16* qsel0 = (u16*)alloc((size_t)BB*DD*2);
  u16* qsel1 = (u16*)alloc((size_t)BB*DD*2);
  u16* qnew0 = (u16*)alloc((size_t)BB*DD*2);
  u16* qnew1 = (u16*)alloc((size_t)BB*DD*2);
  u16* eb0   = (u16*)alloc((size_t)BB*DD*2);
  u16* eb1   = (u16*)alloc((size_t)BB*DD*2);
  float* parties = (float*)alloc((size_t)BB*2*DD*4);
  float* gf  = (float*)alloc((size_t)BB*DD*4);
  float* ef  = (float*)alloc((size_t)BB*DD*4);
  float* GIPa0 = (float*)alloc((size_t)BB*G3*4);
  float* GIPa1 = (float*)alloc((size_t)BB*G3*4);
  float* N0 = (float*)alloc((size_t)BB*G3*4);
  float* N1 = (float*)alloc((size_t)BB*G3*4);
  float* m0 = (float*)alloc(BB*4);
  float* m1 = (float*)alloc(BB*4);
  float* Z0 = (float*)alloc(BB*4);
  float* Z1 = (float*)alloc(BB*4);
  int* spk    = (int*)alloc((size_t)TT*BB*4);
  u16* A1 = (u16*)alloc((size_t)G3*2048*2);
  u16* A2 = (u16*)alloc((size_t)G3*1024*2);
  u16* A3 = (u16*)alloc((size_t)G3*2048*2);
  u16* A4 = (u16*)alloc((size_t)G3*1024*2);
  u16* A5 = (u16*)alloc((size_t)G3*1024*2);
  u16* A6 = (u16*)alloc((size_t)G3*1024*2);
  const size_t need = (size_t)(w - (char*)d_ws);   // ~71 MB < proven 75.5 MB bound
  if (ws_size < need) return;   // fail validation visibly rather than fault

  hipLaunchKernelGGL(setupK, dim3(2048), dim3(256), 0, stream,
                     Wih_g, Whh_g, Wih_p, Whh_p, Wih_e, Whh_e,
                     A1, A2, A3, A4, A5, A6,
                     parties, gf, ef, qsel0, qsel1, qnew0, qnew1, eb0, eb1, spkOH, spk);

  DPar p;
  p.A1 = A1; p.A2 = A2; p.A3 = A3; p.A4 = A4; p.A5 = A5; p.A6 = A6;
  p.feat = feat;
  p.ghist = ghist; p.qsel0 = qsel0; p.qsel1 = qsel1; p.qnew0 = qnew0; p.qnew1 = qnew1;
  p.eb0 = eb0; p.eb1 = eb1;
  p.scoresP = scoresP; p.parties = parties; p.gf = gf; p.ef = ef;
  p.GIPa0 = GIPa0; p.GIPa1 = GIPa1;
  p.N0 = N0; p.N1 = N1; p.m0 = m0; p.m1 = m1; p.Z0 = Z0; p.Z1 = Z1;
  p.bihg = bih_g; p.bhhg = bhh_g; p.bihp = bih_p; p.bhhp = bhh_p;
  p.bihe = bih_e; p.bhhe = bhh_e; p.watt = watt;
  p.spk = spk; p.out = (float*)d_out;

  hipLaunchKernelGGL(kPre, dim3(48), dim3(256), 0, stream, p);
  for (int t = 0; t < TT; ++t)
    hipLaunchKernelGGL(k_step, dim3(240), dim3(256), 0, stream, p, t);
  hipLaunchKernelGGL(kEpi, dim3(64), dim3(256), 0, stream, p);
}

// Round 13
// 4852.943 us; speedup vs baseline: 2.1152x; 1.1719x over previous
//
#include <hip/hip_runtime.h>
#include <stdint.h>

#define TT 128
#define BB 64
#define DD 1024
#define G3 3072

typedef unsigned short u16;
typedef unsigned int u32;
typedef __attribute__((ext_vector_type(8))) short bf16x8;
typedef __attribute__((ext_vector_type(4))) short s16x4;
typedef __attribute__((ext_vector_type(4))) float f32x4;

__device__ __forceinline__ float b2f(u16 h){ u32 u = ((u32)h)<<16; float f; __builtin_memcpy(&f,&u,4); return f; }
__device__ __forceinline__ u16 f2b(float f){ u32 u; __builtin_memcpy(&u,&f,4); u = (u + 0x7fffu + ((u>>16)&1u))>>16; return (u16)u; }
__device__ __forceinline__ float sigm(float x){ return 1.f/(1.f+__expf(-x)); }
__device__ __forceinline__ float tanh_(float x){
  if (x > 10.f) return 1.f;
  if (x < -10.f) return -1.f;
  float e = __expf(2.f*x); return (e-1.f)/(e+1.f);
}

struct DPar {
  const u16 *A1,*A2,*A3,*A4,*A5,*A6;   // bf16 weights
  const float* feat;
  u16 *ghist,*qsel0,*qsel1,*qnew0,*qnew1,*eb0,*eb1;
  float *scoresP;                       // [TT][64][BB] per-colblock score partials
  float *parties,*gf,*ef,*GIPa0,*GIPa1;
  float *N0,*N1,*m0,*m1,*Z0,*Z1;        // online-softmax state (parity)
  const float *bihg,*bhhg,*bihp,*bhhp,*bihe,*bhhe,*watt;
  const int* spk;
  float* out;
};

// ---- A-fragment loaders (bf16 direct; fp32 converted in-flight) ----
__device__ __forceinline__ void loadA(bf16x8& d, const u16* p){ d = *(const bf16x8*)p; }
__device__ __forceinline__ void loadA(bf16x8& d, const float* p){
  f32x4 lo = *(const f32x4*)p;
  f32x4 hi = *(const f32x4*)(p + 4);
  #pragma unroll
  for (int i = 0; i < 4; ++i) { d[i] = (short)f2b(lo[i]); d[i+4] = (short)f2b(hi[i]); }
}

__device__ __forceinline__ void zeroAcc(f32x4 (&a)[2][3]) {
  #pragma unroll
  for (int i = 0; i < 2; ++i) {
    a[i][0] = (f32x4){0,0,0,0}; a[i][1] = (f32x4){0,0,0,0}; a[i][2] = (f32x4){0,0,0,0};
  }
}

// ---- per-wave GEMM: 2 batch-tiles x 3 gate-tiles, NK k-tiles, 4-deep prefetch ----
template<int NK, typename TA>
__device__ __forceinline__ void gemm3(const TA* __restrict__ Ab, int ldA,
    const u16* __restrict__ W0, const u16* __restrict__ W1, const u16* __restrict__ W2,
    f32x4 (&acc)[2][3]) {
  bf16x8 af[4][2], wf[4][3];
  #pragma unroll
  for (int i = 0; i < 3; ++i) {
    const int ko = i * 32;
    loadA(af[i][0], Ab + ko);
    loadA(af[i][1], Ab + (size_t)16*ldA + ko);
    wf[i][0] = *(const bf16x8*)(W0 + ko);
    wf[i][1] = *(const bf16x8*)(W1 + ko);
    wf[i][2] = *(const bf16x8*)(W2 + ko);
  }
  #pragma unroll
  for (int kt = 0; kt < NK; ++kt) {
    const int cur = kt & 3;
    const int pft = kt + 3;
    if (pft < NK) {
      const int nb = pft & 3;
      const int ko = pft * 32;
      loadA(af[nb][0], Ab + ko);
      loadA(af[nb][1], Ab + (size_t)16*ldA + ko);
      wf[nb][0] = *(const bf16x8*)(W0 + ko);
      wf[nb][1] = *(const bf16x8*)(W1 + ko);
      wf[nb][2] = *(const bf16x8*)(W2 + ko);
    }
    #pragma unroll
    for (int bt = 0; bt < 2; ++bt) {
      acc[bt][0] = __builtin_amdgcn_mfma_f32_16x16x32_bf16(af[cur][bt], wf[cur][0], acc[bt][0], 0,0,0);
      acc[bt][1] = __builtin_amdgcn_mfma_f32_16x16x32_bf16(af[cur][bt], wf[cur][1], acc[bt][1], 0,0,0);
      acc[bt][2] = __builtin_amdgcn_mfma_f32_16x16x32_bf16(af[cur][bt], wf[cur][2], acc[bt][2], 0,0,0);
    }
  }
}

// ---- park (write) or accumulate (add) a wave's acc into LDS [32][48] ----
__device__ __forceinline__ void parkAcc48(float* L, f32x4 (&acc)[2][3], int l15, int l4, bool add) {
  #pragma unroll
  for (int bt = 0; bt < 2; ++bt)
    #pragma unroll
    for (int ci = 0; ci < 3; ++ci) {
      const int col = ci*16 + l15;
      #pragma unroll
      for (int q = 0; q < 4; ++q) {
        float* s = L + (bt*16 + l4*4 + q)*48 + col;
        if (add) *s += acc[bt][ci][q]; else *s = acc[bt][ci][q];
      }
    }
}

// ---- fused global GRU (128 blocks: 16 cols x 32 batch): 4-way-K GEMMs + combine ----
__device__ void fusedG(const DPar& p, int t, int bj, int bh, char* ldsraw) {
  float* LI0 = (float*)ldsraw;     // each region [32][48] f32 = 6 KB
  float* LI1 = LI0 + 1536;
  float* LH0 = LI1 + 1536;
  float* LH1 = LH0 + 1536;
  const int tid = (int)threadIdx.x;
  const int kq = tid >> 6;
  const int lane = tid & 63, l15 = lane & 15, l4 = lane >> 4;
  const int lofs = l4 * 8;
  const int j0 = bj * 16;
  const int b0 = bh * 32;
  const size_t r0 = (size_t)(j0 + l15);
  const u16* qsel = (t & 1) ? p.qsel1 : p.qsel0;
  f32x4 acc[2][3];
  zeroAcc(acc);
  { // i-part: X = [feat | qsel], K=2048 quarters of 512
    const int kw = (kq < 2) ? kq*512 : 1024 + (kq - 2)*512;
    const u16* W0 = p.A1 + (r0       )*2048 + kw + lofs;
    const u16* W1 = p.A1 + (r0 + 1024)*2048 + kw + lofs;
    const u16* W2 = p.A1 + (r0 + 2048)*2048 + kw + lofs;
    if (kq < 2) gemm3<16>(p.feat + (size_t)t*BB*DD + (size_t)(b0+l15)*DD + kq*512 + lofs, DD, W0, W1, W2, acc);
    else        gemm3<16>(qsel + (size_t)(b0+l15)*DD + (kq-2)*512 + lofs, DD, W0, W1, W2, acc);
  }
  if (kq == 1) parkAcc48(LI0, acc, l15, l4, false);
  if (kq == 3) parkAcc48(LI1, acc, l15, l4, false);
  __syncthreads();
  if (kq == 0) parkAcc48(LI0, acc, l15, l4, true);
  if (kq == 2) parkAcc48(LI1, acc, l15, l4, true);
  zeroAcc(acc);
  if (t) { // h-part: g_{t-1}, K=1024 quarters of 256
    const int kw = kq*256;
    const u16* W0 = p.A2 + (r0       )*1024 + kw + lofs;
    const u16* W1 = p.A2 + (r0 + 1024)*1024 + kw + lofs;
    const u16* W2 = p.A2 + (r0 + 2048)*1024 + kw + lofs;
    gemm3<8>(p.ghist + (size_t)(t-1)*BB*DD + (size_t)(b0+l15)*DD + kw + lofs, DD, W0, W1, W2, acc);
  }
  if (kq == 1) parkAcc48(LH0, acc, l15, l4, false);
  if (kq == 3) parkAcc48(LH1, acc, l15, l4, false);
  __syncthreads();
  if (kq == 0) parkAcc48(LH0, acc, l15, l4, true);
  if (kq == 2) parkAcc48(LH1, acc, l15, l4, true);
  __syncthreads();
  if (tid < 64) {
    const int lb = tid >> 1, b = b0 + lb, jjb = (tid & 1) * 8;
    const float* i0 = LI0 + lb*48; const float* i1 = LI1 + lb*48;
    const float* h0 = LH0 + lb*48; const float* h1 = LH1 + lb*48;
    float gv8[8]; float scp = 0.f;
    #pragma unroll
    for (int i = 0; i < 8; ++i) {
      const int jj = jjb + i, j = j0 + jj;
      const float ir = i0[jj]    + i1[jj]    + p.bihg[j];
      const float iz = i0[16+jj] + i1[16+jj] + p.bihg[1024+j];
      const float in_= i0[32+jj] + i1[32+jj] + p.bihg[2048+j];
      const float hr = h0[jj]    + h1[jj]    + p.bhhg[j];
      const float hz = h0[16+jj] + h1[16+jj] + p.bhhg[1024+j];
      const float hn = h0[32+jj] + h1[32+jj] + p.bhhg[2048+j];
      const float r_ = sigm(ir + hr);
      const float z_ = sigm(iz + hz);
      const float n_ = tanh_(in_ + r_*hn);
      const float gp = p.gf[(size_t)b*DD + j];
      const float gv = (1.f - z_)*n_ + z_*gp;
      p.gf[(size_t)b*DD + j] = gv;
      gv8[i] = gv;
      scp += gv * p.watt[j];
    }
    bf16x8 hh;
    #pragma unroll
    for (int i = 0; i < 8; ++i) hh[i] = (short)f2b(gv8[i]);
    *(bf16x8*)(p.ghist + (size_t)t*BB*DD + (size_t)b*DD + j0 + jjb) = hh;
    scp += __shfl_xor(scp, 1);
    if ((tid & 1) == 0) p.scoresP[(size_t)t*64*BB + (size_t)bj*BB + b] = scp;
  }
}

// ---- fused emotion GRU (128 blocks: 16 cols x 32 batch): emotion step td = t-1 ----
__device__ void fusedE(const DPar& p, int t, int bj, int bh, char* ldsraw) {
  const int td = t - 1;
  float* LI0 = (float*)ldsraw;
  float* LI1 = LI0 + 1536;
  float* LH0 = LI1 + 1536;
  float* LH1 = LH0 + 1536;
  const int tid = (int)threadIdx.x;
  const int kq = tid >> 6;
  const int lane = tid & 63, l15 = lane & 15, l4 = lane >> 4;
  const int lofs = l4 * 8;
  const int j0 = bj * 16;
  const int b0 = bh * 32;
  const size_t r0 = (size_t)(j0 + l15);
  const u16* qn = ((t-1) & 1) ? p.qnew1 : p.qnew0;   // qnew_{t-1}
  f32x4 acc[2][3];
  zeroAcc(acc);
  { // i-part: qnew_{td}, K=1024 quarters
    const int kw = kq*256;
    const u16* W0 = p.A5 + (r0       )*1024 + kw + lofs;
    const u16* W1 = p.A5 + (r0 + 1024)*1024 + kw + lofs;
    const u16* W2 = p.A5 + (r0 + 2048)*1024 + kw + lofs;
    gemm3<8>(qn + (size_t)(b0+l15)*DD + kw + lofs, DD, W0, W1, W2, acc);
  }
  if (kq == 1) parkAcc48(LI0, acc, l15, l4, false);
  if (kq == 3) parkAcc48(LI1, acc, l15, l4, false);
  __syncthreads();
  if (kq == 0) parkAcc48(LI0, acc, l15, l4, true);
  if (kq == 2) parkAcc48(LI1, acc, l15, l4, true);
  zeroAcc(acc);
  if (td > 0) { // h-part: e_{td-1}
    const u16* ebr = (t & 1) ? p.eb1 : p.eb0;
    const int kw = kq*256;
    const u16* W0 = p.A6 + (r0       )*1024 + kw + lofs;
    const u16* W1 = p.A6 + (r0 + 1024)*1024 + kw + lofs;
    const u16* W2 = p.A6 + (r0 + 2048)*1024 + kw + lofs;
    gemm3<8>(ebr + (size_t)(b0+l15)*DD + kw + lofs, DD, W0, W1, W2, acc);
  }
  if (kq == 1) parkAcc48(LH0, acc, l15, l4, false);
  if (kq == 3) parkAcc48(LH1, acc, l15, l4, false);
  __syncthreads();
  if (kq == 0) parkAcc48(LH0, acc, l15, l4, true);
  if (kq == 2) parkAcc48(LH1, acc, l15, l4, true);
  __syncthreads();
  if (tid < 64) {
    const int lb = tid >> 1, b = b0 + lb, jjb = (tid & 1) * 8;
    const float* i0 = LI0 + lb*48; const float* i1 = LI1 + lb*48;
    const float* h0 = LH0 + lb*48; const float* h1 = LH1 + lb*48;
    float ev8[8];
    #pragma unroll
    for (int i = 0; i < 8; ++i) {
      const int jj = jjb + i, j = j0 + jj;
      const float ir = i0[jj]    + i1[jj]    + p.bihe[j];
      const float iz = i0[16+jj] + i1[16+jj] + p.bihe[1024+j];
      const float in_= i0[32+jj] + i1[32+jj] + p.bihe[2048+j];
      const float hr = h0[jj]    + h1[jj]    + p.bhhe[j];
      const float hz = h0[16+jj] + h1[16+jj] + p.bhhe[1024+j];
      const float hn = h0[32+jj] + h1[32+jj] + p.bhhe[2048+j];
      const float r_ = sigm(ir + hr);
      const float z_ = sigm(iz + hz);
      const float n_ = tanh_(in_ + r_*hn);
      const float ep = p.ef[(size_t)b*DD + j];
      const float ev = (1.f - z_)*n_ + z_*ep;
      p.ef[(size_t)b*DD + j] = ev;
      ev8[i] = ev;
    }
    float* orow = p.out + (size_t)td*BB*DD + (size_t)b*DD + j0 + jjb;
    *(f32x4*)orow       = (f32x4){ev8[0], ev8[1], ev8[2], ev8[3]};
    *(f32x4*)(orow + 4) = (f32x4){ev8[4], ev8[5], ev8[6], ev8[7]};
    u16* ebw = ((t-1) & 1) ? p.eb1 : p.eb0;
    bf16x8 ee;
    #pragma unroll
    for (int i = 0; i < 8; ++i) ee[i] = (short)f2b(ev8[i]);
    *(bf16x8*)(ebw + (size_t)b*DD + j0 + jjb) = ee;
  }
}

// ---- fused party GRU + inline online-softmax attention (128 blocks: 16 cols x 32 batch) ----
__device__ void fusedP(const DPar& p, int t, int bj, int bh, char* ldsraw) {
  float* LI0 = (float*)ldsraw;     // GW = ghist(t-1) @ Wp2 slice
  float* LI1 = LI0 + 1536;
  float* LH0 = LI1 + 1536;         // GHP = qsel_t @ Whh_p slice
  float* LH1 = LH0 + 1536;
  const int tid = (int)threadIdx.x;
  const int kq = tid >> 6;
  const int lane = tid & 63, l15 = lane & 15, l4 = lane >> 4;
  const int lofs = l4 * 8;
  const int j0 = bj * 16;
  const int b0 = bh * 32;
  const size_t r0 = (size_t)(j0 + l15);
  const u16* qsel = (t & 1) ? p.qsel1 : p.qsel0;
  f32x4 acc[2][3];
  zeroAcc(acc);
  if (t) { // GW: ghist(t-1) against second K-half of A3
    const int kw = 1024 + kq*256;
    const u16* W0 = p.A3 + (r0       )*2048 + kw + lofs;
    const u16* W1 = p.A3 + (r0 + 1024)*2048 + kw + lofs;
    const u16* W2 = p.A3 + (r0 + 2048)*2048 + kw + lofs;
    gemm3<8>(p.ghist + (size_t)(t-1)*BB*DD + (size_t)(b0+l15)*DD + kq*256 + lofs, DD, W0, W1, W2, acc);
  }
  if (kq == 1) parkAcc48(LI0, acc, l15, l4, false);
  if (kq == 3) parkAcc48(LI1, acc, l15, l4, false);
  __syncthreads();
  if (kq == 0) parkAcc48(LI0, acc, l15, l4, true);
  if (kq == 2) parkAcc48(LI1, acc, l15, l4, true);
  zeroAcc(acc);
  { // GHP: qsel_t @ Whh_p^T (A4, K=1024 quarters)
    const int kw = kq*256;
    const u16* W0 = p.A4 + (r0       )*1024 + kw + lofs;
    const u16* W1 = p.A4 + (r0 + 1024)*1024 + kw + lofs;
    const u16* W2 = p.A4 + (r0 + 2048)*1024 + kw + lofs;
    gemm3<8>(qsel + (size_t)(b0+l15)*DD + kw + lofs, DD, W0, W1, W2, acc);
  }
  if (kq == 1) parkAcc48(LH0, acc, l15, l4, false);
  if (kq == 3) parkAcc48(LH1, acc, l15, l4, false);
  __syncthreads();
  if (kq == 0) parkAcc48(LH0, acc, l15, l4, true);
  if (kq == 2) parkAcc48(LH1, acc, l15, l4, true);
  __syncthreads();
  if (tid < 64) {
    const int lb = tid >> 1, b = b0 + lb, jjb = (tid & 1) * 8;
    float mN = -1e30f, Zn = 0.f, scl = 0.f, wn = 0.f, invZ = 0.f;
    if (t > 0) {
      const float* sp = p.scoresP + (size_t)(t-1)*64*BB + b;
      float s = 0.f;
      #pragma unroll
      for (int pp = 0; pp < 64; ++pp) s += sp[pp*BB];
      const float mo = ((t-1) & 1 ? p.m1 : p.m0)[b];
      const float Zo = ((t-1) & 1 ? p.Z1 : p.Z0)[b];
      mN  = fmaxf(mo, s);
      scl = __expf(mo - mN);
      wn  = __expf(s - mN);
      Zn  = Zo*scl + wn;
      invZ = 1.f / Zn;
    }
    float* Nw = (t & 1) ? p.N1 : p.N0;
    const float* Nr = (t & 1) ? p.N0 : p.N1;
    const int spkc = p.spk[t*BB + b];
    const int spkn = (t+1 < TT) ? p.spk[(t+1)*BB + b] : spkc;
    float* prow = p.parties + (size_t)(b*2 + spkc)*DD;
    const float* orow = p.parties + (size_t)(b*2 + spkn)*DD;
    const float* Gia = ((t & 1) ? p.GIPa1 : p.GIPa0) + (size_t)b*G3;
    const float* i0 = LI0 + lb*48; const float* i1 = LI1 + lb*48;
    const float* h0 = LH0 + lb*48; const float* h1 = LH1 + lb*48;
    u16* qselw = ((t+1) & 1) ? p.qsel1 : p.qsel0;
    u16* qneww = (t & 1) ? p.qnew1 : p.qnew0;
    float qn8[8], qs8[8];
    #pragma unroll
    for (int i = 0; i < 8; ++i) {
      const int jj = jjb + i, j = j0 + jj;
      float gipb[3];
      #pragma unroll
      for (int g = 0; g < 3; ++g) {
        const size_t col = (size_t)g*1024 + j;
        const float GW = i0[g*16+jj] + i1[g*16+jj];
        float Nn = 0.f;
        if (t > 0) Nn = Nr[(size_t)b*G3 + col]*scl + wn*GW;
        Nw[(size_t)b*G3 + col] = Nn;
        gipb[g] = Nn * invZ;
      }
      const float gi_r = Gia[j]      + gipb[0] + p.bihp[j];
      const float gi_z = Gia[1024+j] + gipb[1] + p.bihp[1024+j];
      const float gi_n = Gia[2048+j] + gipb[2] + p.bihp[2048+j];
      const float gh_r = h0[jj]    + h1[jj]    + p.bhhp[j];
      const float gh_z = h0[16+jj] + h1[16+jj] + p.bhhp[1024+j];
      const float gh_n = h0[32+jj] + h1[32+jj] + p.bhhp[2048+j];
      const float r_ = sigm(gi_r + gh_r);
      const float z_ = sigm(gi_z + gh_z);
      const float n_ = tanh_(gi_n + r_*gh_n);
      const float h  = prow[j];
      const float qv = (1.f - z_)*n_ + z_*h;
      prow[j] = qv;
      qn8[i] = qv;
      qs8[i] = (spkn == spkc) ? qv : orow[j];
    }
    if (bj == 0 && (tid & 1) == 0) {
      ((t & 1) ? p.m1 : p.m0)[b] = mN;
      ((t & 1) ? p.Z1 : p.Z0)[b] = Zn;
    }
    bf16x8 qn, qs;
    #pragma unroll
    for (int i = 0; i < 8; ++i) { qn[i] = (short)f2b(qn8[i]); qs[i] = (short)f2b(qs8[i]); }
    *(bf16x8*)(qneww + (size_t)b*DD + j0 + jjb) = qn;
    *(bf16x8*)(qselw + (size_t)b*DD + j0 + jjb) = qs;
  }
}

// ---- 64-col x 32-batch GEMM tile (2 K-halves x 2 N-halves, 2 bt), for GIPa ----
template<typename TA>
__device__ __attribute__((noinline)) void gemm_frag(
    const TA* __restrict__ A, const u16* __restrict__ W, int ldW,
    int k0, int n0, int b0, float* __restrict__ C, float* red) {
  const int tid = threadIdx.x;
  const int wv  = tid >> 6;
  const int kh  = wv >> 1;
  const int nh  = wv & 1;
  const int lane = tid & 63;
  const int l15 = lane & 15;
  const int l4  = lane >> 4;
  const TA*  Ab = A + (size_t)(b0 + l15) * DD + kh * 512 + l4 * 8;
  const u16* Wb = W + (size_t)(n0 + nh*32 + l15) * ldW + k0 + kh * 512 + l4 * 8;

  f32x4 acc[2][2];
  #pragma unroll
  for (int i = 0; i < 2; ++i) { acc[i][0] = (f32x4){0,0,0,0}; acc[i][1] = (f32x4){0,0,0,0}; }

  bf16x8 af[4][2], wf[4][2];
  #pragma unroll
  for (int i = 0; i < 3; ++i) {
    const int ko = i * 32;
    loadA(af[i][0], Ab + ko);
    loadA(af[i][1], Ab + (size_t)16*DD + ko);
    wf[i][0] = *(const bf16x8*)(Wb + ko);
    wf[i][1] = *(const bf16x8*)(Wb + (size_t)16*ldW + ko);
  }
  #pragma unroll
  for (int kt = 0; kt < 16; ++kt) {
    const int cur = kt & 3;
    const int pft = kt + 3;
    if (pft < 16) {
      const int nb = pft & 3;
      const int ko = pft * 32;
      loadA(af[nb][0], Ab + ko);
      loadA(af[nb][1], Ab + (size_t)16*DD + ko);
      wf[nb][0] = *(const bf16x8*)(Wb + ko);
      wf[nb][1] = *(const bf16x8*)(Wb + (size_t)16*ldW + ko);
    }
    #pragma unroll
    for (int bt = 0; bt < 2; ++bt) {
      acc[bt][0] = __builtin_amdgcn_mfma_f32_16x16x32_bf16(af[cur][bt], wf[cur][0], acc[bt][0], 0,0,0);
      acc[bt][1] = __builtin_amdgcn_mfma_f32_16x16x32_bf16(af[cur][bt], wf[cur][1], acc[bt][1], 0,0,0);
    }
  }
  if (kh == 1) {
    #pragma unroll
    for (int bt = 0; bt < 2; ++bt)
      #pragma unroll
      for (int nt = 0; nt < 2; ++nt)
        #pragma unroll
        for (int q = 0; q < 4; ++q)
          red[(bt*16 + l4*4 + q)*64 + nh*32 + nt*16 + l15] = acc[bt][nt][q];
  }
  __syncthreads();
  if (kh == 0) {
    #pragma unroll
    for (int bt = 0; bt < 2; ++bt)
      #pragma unroll
      for (int nt = 0; nt < 2; ++nt)
        #pragma unroll
        for (int q = 0; q < 4; ++q) {
          const int row = bt*16 + l4*4 + q;
          const int col = nh*32 + nt*16 + l15;
          C[(size_t)(b0 + row)*G3 + n0 + col] = acc[bt][nt][q] + red[row*64 + col];
        }
  }
}

// ---- one dispatch per step: fusedG(128)|fusedE(128)|fusedP(128)|GIPa(96) = 480 ----
__global__ void __launch_bounds__(256) k_step(DPar p, int t) {
  __shared__ __align__(16) char lds[24576];
  const int blk = (int)blockIdx.x;
  if (blk < 128)       fusedG(p, t, blk>>1, blk&1, lds);
  else if (blk < 256)  { if (t) fusedE(p, t, (blk-128)>>1, (blk-128)&1, lds); }
  else if (blk < 384)  fusedP(p, t, (blk-256)>>1, (blk-256)&1, lds);
  else { if (t + 1 < TT) {
           const int r = blk - 384;
           gemm_frag(p.feat + (size_t)(t+1)*BB*DD, p.A3, 2048, 0, (r>>1)*64, (r&1)*32,
                     ((t+1)&1) ? p.GIPa1 : p.GIPa0, (float*)lds);
         } }
}

// ---- prologue: GIPa(0) ----
__global__ void __launch_bounds__(256) kPre(DPar p) {
  __shared__ __align__(16) float red[2048];
  const int r = (int)blockIdx.x;
  gemm_frag(p.feat, p.A3, 2048, 0, (r>>1)*64, (r&1)*32, p.GIPa0, red);
}

// ---- epilogue: emotion step 127 ----
__global__ void __launch_bounds__(256) kEpi(DPar p) {
  __shared__ __align__(16) char lds[24576];
  fusedE(p, TT, (int)blockIdx.x>>1, (int)blockIdx.x&1, lds);
}

// ---- setup: weight fp32 -> bf16 cast + state zero + speaker idx (every launch) ----
__global__ void setupK(const float* __restrict__ Wg, const float* __restrict__ Whg,
                       const float* __restrict__ Wp, const float* __restrict__ Whp,
                       const float* __restrict__ We, const float* __restrict__ Whe,
                       u16* A1, u16* A2, u16* A3, u16* A4, u16* A5, u16* A6,
                       float* parties, float* gf, float* ef,
                       u16* qsel0, u16* qsel1, u16* qnew0, u16* qnew1, u16* eb0, u16* eb1,
                       const float* spkOH, int* spk) {
  long gid = (long)blockIdx.x*256 + threadIdx.x;
  if (gid < BB*2*DD) parties[gid] = 0.f;
  if (gid < BB*DD) {
    gf[gid] = 0.f; ef[gid] = 0.f;
    qsel0[gid] = 0; qsel1[gid] = 0; qnew0[gid] = 0; qnew1[gid] = 0; eb0[gid] = 0; eb1[gid] = 0;
  }
  if (gid < TT*BB) spk[gid] = (spkOH[(size_t)gid*2 + 1] > 0.5f) ? 1 : 0;
  const long n1 = (long)G3*2048/4, n2 = (long)G3*1024/4;
  const long tot = 2*n1 + 4*n2;
  const long stride = (long)gridDim.x*256;
  for (long i = gid; i < tot; i += stride) {
    const float* src; u16* dst; long o = i;
    if (o < n1) { src = Wg;  dst = A1; }
    else { o -= n1;
      if (o < n2) { src = Whg; dst = A2; }
      else { o -= n2;
        if (o < n1) { src = Wp; dst = A3; }
        else { o -= n1;
          if (o < n2) { src = Whp; dst = A4; }
          else { o -= n2;
            if (o < n2) { src = We; dst = A5; }
            else { o -= n2; src = Whe; dst = A6; }
          }
        }
      }
    }
    f32x4 v = *(const f32x4*)(src + o*4);
    s16x4 w;
    w[0] = (short)f2b(v[0]); w[1] = (short)f2b(v[1]);
    w[2] = (short)f2b(v[2]); w[3] = (short)f2b(v[3]);
    *(s16x4*)(dst + o*4) = w;
  }
}

extern "C" void kernel_launch(void* const* d_in, const int* in_sizes, int n_in,
                              void* d_out, int out_size, void* d_ws, size_t ws_size,
                              hipStream_t stream) {
  const float* feat  = (const float*)d_in[0];
  const float* spkOH = (const float*)d_in[1];
  const float* Wih_g = (const float*)d_in[2];
  const float* Whh_g = (const float*)d_in[3];
  const float* bih_g = (const float*)d_in[4];
  const float* bhh_g = (const float*)d_in[5];
  const float* Wih_p = (const float*)d_in[6];
  const float* Whh_p = (const float*)d_in[7];
  const float* bih_p = (const float*)d_in[8];
  const float* bhh_p = (const float*)d_in[9];
  const float* Wih_e = (const float*)d_in[10];
  const float* Whh_e = (const float*)d_in[11];
  const float* bih_e = (const float*)d_in[12];
  const float* bhh_e = (const float*)d_in[13];
  const float* watt  = (const float*)d_in[14];

  char* w = (char*)d_ws;
  auto alloc = [&](size_t bytes) -> char* {
    char* r = w; w += (bytes + 255) & ~(size_t)255; return r;
  };
  u16* ghist = (u16*)alloc((size_t)TT*BB*DD*2);
  float* scoresP = (float*)alloc((size_t)TT*64*BB*4);
  u16* qsel0 = (u16*)alloc((size_t)BB*DD*2);
  u16* qsel1 = (u16*)alloc((size_t)BB*DD*2);
  u16* qnew0 = (u16*)alloc((size_t)BB*DD*2);
  u16* qnew1 = (u16*)alloc((size_t)BB*DD*2);
  u16* eb0   = (u16*)alloc((size_t)BB*DD*2);
  u16* eb1   = (u16*)alloc((size_t)BB*DD*2);
  float* parties = (float*)alloc((size_t)BB*2*DD*4);
  float* gf  = (float*)alloc((size_t)BB*DD*4);
  float* ef  = (float*)alloc((size_t)BB*DD*4);
  float* GIPa0 = (float*)alloc((size_t)BB*G3*4);
  float* GIPa1 = (float*)alloc((size_t)BB*G3*4);
  float* N0 = (float*)alloc((size_t)BB*G3*4);
  float* N1 = (float*)alloc((size_t)BB*G3*4);
  float* m0 = (float*)alloc(BB*4);
  float* m1 = (float*)alloc(BB*4);
  float* Z0 = (float*)alloc(BB*4);
  float* Z1 = (float*)alloc(BB*4);
  int* spk    = (int*)alloc((size_t)TT*BB*4);
  u16* A1 = (u16*)alloc((size_t)G3*2048*2);
  u16* A2 = (u16*)alloc((size_t)G3*1024*2);
  u16* A3 = (u16*)alloc((size_t)G3*2048*2);
  u16* A4 = (u16*)alloc((size_t)G3*1024*2);
  u16* A5 = (u16*)alloc((size_t)G3*1024*2);
  u16* A6 = (u16*)alloc((size_t)G3*1024*2);
  const size_t need = (size_t)(w - (char*)d_ws);   // ~71 MB < proven 75.5 MB bound
  if (ws_size < need) return;   // fail validation visibly rather than fault

  hipLaunchKernelGGL(setupK, dim3(2048), dim3(256), 0, stream,
                     Wih_g, Whh_g, Wih_p, Whh_p, Wih_e, Whh_e,
                     A1, A2, A3, A4, A5, A6,
                     parties, gf, ef, qsel0, qsel1, qnew0, qnew1, eb0, eb1, spkOH, spk);

  DPar p;
  p.A1 = A1; p.A2 = A2; p.A3 = A3; p.A4 = A4; p.A5 = A5; p.A6 = A6;
  p.feat = feat;
  p.ghist = ghist; p.qsel0 = qsel0; p.qsel1 = qsel1; p.qnew0 = qnew0; p.qnew1 = qnew1;
  p.eb0 = eb0; p.eb1 = eb1;
  p.scoresP = scoresP; p.parties = parties; p.gf = gf; p.ef = ef;
  p.GIPa0 = GIPa0; p.GIPa1 = GIPa1;
  p.N0 = N0; p.N1 = N1; p.m0 = m0; p.m1 = m1; p.Z0 = Z0; p.Z1 = Z1;
  p.bihg = bih_g; p.bhhg = bhh_g; p.bihp = bih_p; p.bhhp = bhh_p;
  p.bihe = bih_e; p.bhhe = bhh_e; p.watt = watt;
  p.spk = spk; p.out = (float*)d_out;

  hipLaunchKernelGGL(kPre, dim3(96), dim3(256), 0, stream, p);
  for (int t = 0; t < TT; ++t)
    hipLaunchKernelGGL(k_step, dim3(480), dim3(256), 0, stream, p, t);
  hipLaunchKernelGGL(kEpi, dim3(128), dim3(256), 0, stream, p);
}

// Round 14
// 4803.558 us; speedup vs baseline: 2.1369x; 1.0103x over previous
//
#include <hip/hip_runtime.h>
#include <stdint.h>

#define TT 128
#define BB 64
#define DD 1024
#define G3 3072

typedef unsigned short u16;
typedef unsigned int u32;
typedef __attribute__((ext_vector_type(8))) short bf16x8;
typedef __attribute__((ext_vector_type(4))) short s16x4;
typedef __attribute__((ext_vector_type(4))) float f32x4;

__device__ __forceinline__ float b2f(u16 h){ u32 u = ((u32)h)<<16; float f; __builtin_memcpy(&f,&u,4); return f; }
__device__ __forceinline__ u16 f2b(float f){ u32 u; __builtin_memcpy(&u,&f,4); u = (u + 0x7fffu + ((u>>16)&1u))>>16; return (u16)u; }
__device__ __forceinline__ float sigm(float x){ return 1.f/(1.f+__expf(-x)); }
__device__ __forceinline__ float tanh_(float x){
  if (x > 10.f) return 1.f;
  if (x < -10.f) return -1.f;
  float e = __expf(2.f*x); return (e-1.f)/(e+1.f);
}

struct DPar {
  const u16 *A1,*A2,*A3,*A4,*A5,*A6;   // bf16 weights
  const float* feat;
  u16 *ghist,*qsel0,*qsel1,*qnew0,*qnew1,*eb0,*eb1;
  float *scoresP;                       // [TT][64][BB] per-colblock score partials
  float *parties,*gf,*ef,*GIPa0,*GIPa1;
  float *N0,*N1,*m0,*m1,*Z0,*Z1;        // online-softmax state (parity)
  const float *bihg,*bhhg,*bihp,*bhhp,*bihe,*bhhe,*watt;
  const int* spk;
  float* out;
};

// ---- A-fragment loaders (bf16 direct; fp32 converted in-flight) ----
__device__ __forceinline__ void loadA(bf16x8& d, const u16* p){ d = *(const bf16x8*)p; }
__device__ __forceinline__ void loadA(bf16x8& d, const float* p){
  f32x4 lo = *(const f32x4*)p;
  f32x4 hi = *(const f32x4*)(p + 4);
  #pragma unroll
  for (int i = 0; i < 4; ++i) { d[i] = (short)f2b(lo[i]); d[i+4] = (short)f2b(hi[i]); }
}

__device__ __forceinline__ void zeroAcc(f32x4 (&a)[2][3]) {
  #pragma unroll
  for (int i = 0; i < 2; ++i) {
    a[i][0] = (f32x4){0,0,0,0}; a[i][1] = (f32x4){0,0,0,0}; a[i][2] = (f32x4){0,0,0,0};
  }
}

// ---- per-wave GEMM: 2 batch-tiles x 3 gate-tiles, NK k-tiles, 5-deep ring ----
template<int NK, typename TA>
__device__ __forceinline__ void gemm3(const TA* __restrict__ Ab, int ldA,
    const u16* __restrict__ W0, const u16* __restrict__ W1, const u16* __restrict__ W2,
    f32x4 (&acc)[2][3]) {
  bf16x8 af[5][2], wf[5][3];
  #pragma unroll
  for (int i = 0; i < 4; ++i) {
    const int ko = i * 32;
    loadA(af[i][0], Ab + ko);
    loadA(af[i][1], Ab + (size_t)16*ldA + ko);
    wf[i][0] = *(const bf16x8*)(W0 + ko);
    wf[i][1] = *(const bf16x8*)(W1 + ko);
    wf[i][2] = *(const bf16x8*)(W2 + ko);
  }
  #pragma unroll
  for (int kt = 0; kt < NK; ++kt) {
    const int cur = kt % 5;
    const int pft = kt + 4;
    if (pft < NK) {
      const int nb = pft % 5;
      const int ko = pft * 32;
      loadA(af[nb][0], Ab + ko);
      loadA(af[nb][1], Ab + (size_t)16*ldA + ko);
      wf[nb][0] = *(const bf16x8*)(W0 + ko);
      wf[nb][1] = *(const bf16x8*)(W1 + ko);
      wf[nb][2] = *(const bf16x8*)(W2 + ko);
    }
    #pragma unroll
    for (int bt = 0; bt < 2; ++bt) {
      acc[bt][0] = __builtin_amdgcn_mfma_f32_16x16x32_bf16(af[cur][bt], wf[cur][0], acc[bt][0], 0,0,0);
      acc[bt][1] = __builtin_amdgcn_mfma_f32_16x16x32_bf16(af[cur][bt], wf[cur][1], acc[bt][1], 0,0,0);
      acc[bt][2] = __builtin_amdgcn_mfma_f32_16x16x32_bf16(af[cur][bt], wf[cur][2], acc[bt][2], 0,0,0);
    }
  }
}

// ---- park (write) or accumulate (add) a wave's acc into LDS [32][48] ----
__device__ __forceinline__ void parkAcc48(float* L, f32x4 (&acc)[2][3], int l15, int l4, bool add) {
  #pragma unroll
  for (int bt = 0; bt < 2; ++bt)
    #pragma unroll
    for (int ci = 0; ci < 3; ++ci) {
      const int col = ci*16 + l15;
      #pragma unroll
      for (int q = 0; q < 4; ++q) {
        float* s = L + (bt*16 + l4*4 + q)*48 + col;
        if (add) *s += acc[bt][ci][q]; else *s = acc[bt][ci][q];
      }
    }
}

// ---- fused global GRU (128 blocks: 16 cols x 32 batch): 4-way-K GEMMs + combine ----
__device__ void fusedG(const DPar& p, int t, int bj, int bh, char* ldsraw) {
  float* LI0 = (float*)ldsraw;     // each region [32][48] f32 = 6 KB
  float* LI1 = LI0 + 1536;
  float* LH0 = LI1 + 1536;
  float* LH1 = LH0 + 1536;
  const int tid = (int)threadIdx.x;
  const int kq = tid >> 6;
  const int lane = tid & 63, l15 = lane & 15, l4 = lane >> 4;
  const int lofs = l4 * 8;
  const int j0 = bj * 16;
  const int b0 = bh * 32;
  const size_t r0 = (size_t)(j0 + l15);
  const u16* qsel = (t & 1) ? p.qsel1 : p.qsel0;
  f32x4 acc[2][3];
  zeroAcc(acc);
  { // i-part: X = [feat | qsel], K=2048 quarters of 512
    const int kw = (kq < 2) ? kq*512 : 1024 + (kq - 2)*512;
    const u16* W0 = p.A1 + (r0       )*2048 + kw + lofs;
    const u16* W1 = p.A1 + (r0 + 1024)*2048 + kw + lofs;
    const u16* W2 = p.A1 + (r0 + 2048)*2048 + kw + lofs;
    if (kq < 2) gemm3<16>(p.feat + (size_t)t*BB*DD + (size_t)(b0+l15)*DD + kq*512 + lofs, DD, W0, W1, W2, acc);
    else        gemm3<16>(qsel + (size_t)(b0+l15)*DD + (kq-2)*512 + lofs, DD, W0, W1, W2, acc);
  }
  if (kq == 1) parkAcc48(LI0, acc, l15, l4, false);
  if (kq == 3) parkAcc48(LI1, acc, l15, l4, false);
  __syncthreads();
  if (kq == 0) parkAcc48(LI0, acc, l15, l4, true);
  if (kq == 2) parkAcc48(LI1, acc, l15, l4, true);
  zeroAcc(acc);
  if (t) { // h-part: g_{t-1}, K=1024 quarters of 256
    const int kw = kq*256;
    const u16* W0 = p.A2 + (r0       )*1024 + kw + lofs;
    const u16* W1 = p.A2 + (r0 + 1024)*1024 + kw + lofs;
    const u16* W2 = p.A2 + (r0 + 2048)*1024 + kw + lofs;
    gemm3<8>(p.ghist + (size_t)(t-1)*BB*DD + (size_t)(b0+l15)*DD + kw + lofs, DD, W0, W1, W2, acc);
  }
  if (kq == 1) parkAcc48(LH0, acc, l15, l4, false);
  if (kq == 3) parkAcc48(LH1, acc, l15, l4, false);
  __syncthreads();
  if (kq == 0) parkAcc48(LH0, acc, l15, l4, true);
  if (kq == 2) parkAcc48(LH1, acc, l15, l4, true);
  __syncthreads();
  if (tid < 64) {
    const int lb = tid >> 1, b = b0 + lb, jjb = (tid & 1) * 8;
    const float* i0 = LI0 + lb*48; const float* i1 = LI1 + lb*48;
    const float* h0 = LH0 + lb*48; const float* h1 = LH1 + lb*48;
    float gv8[8]; float scp = 0.f;
    #pragma unroll
    for (int i = 0; i < 8; ++i) {
      const int jj = jjb + i, j = j0 + jj;
      const float ir = i0[jj]    + i1[jj]    + p.bihg[j];
      const float iz = i0[16+jj] + i1[16+jj] + p.bihg[1024+j];
      const float in_= i0[32+jj] + i1[32+jj] + p.bihg[2048+j];
      const float hr = h0[jj]    + h1[jj]    + p.bhhg[j];
      const float hz = h0[16+jj] + h1[16+jj] + p.bhhg[1024+j];
      const float hn = h0[32+jj] + h1[32+jj] + p.bhhg[2048+j];
      const float r_ = sigm(ir + hr);
      const float z_ = sigm(iz + hz);
      const float n_ = tanh_(in_ + r_*hn);
      const float gp = p.gf[(size_t)b*DD + j];
      const float gv = (1.f - z_)*n_ + z_*gp;
      p.gf[(size_t)b*DD + j] = gv;
      gv8[i] = gv;
      scp += gv * p.watt[j];
    }
    bf16x8 hh;
    #pragma unroll
    for (int i = 0; i < 8; ++i) hh[i] = (short)f2b(gv8[i]);
    *(bf16x8*)(p.ghist + (size_t)t*BB*DD + (size_t)b*DD + j0 + jjb) = hh;
    scp += __shfl_xor(scp, 1);
    if ((tid & 1) == 0) p.scoresP[(size_t)t*64*BB + (size_t)bj*BB + b] = scp;
  }
}

// ---- fused emotion GRU (128 blocks: 16 cols x 32 batch): emotion step td = t-1 ----
__device__ void fusedE(const DPar& p, int t, int bj, int bh, char* ldsraw) {
  const int td = t - 1;
  float* LI0 = (float*)ldsraw;
  float* LI1 = LI0 + 1536;
  float* LH0 = LI1 + 1536;
  float* LH1 = LH0 + 1536;
  const int tid = (int)threadIdx.x;
  const int kq = tid >> 6;
  const int lane = tid & 63, l15 = lane & 15, l4 = lane >> 4;
  const int lofs = l4 * 8;
  const int j0 = bj * 16;
  const int b0 = bh * 32;
  const size_t r0 = (size_t)(j0 + l15);
  const u16* qn = ((t-1) & 1) ? p.qnew1 : p.qnew0;   // qnew_{t-1}
  f32x4 acc[2][3];
  zeroAcc(acc);
  { // i-part: qnew_{td}, K=1024 quarters
    const int kw = kq*256;
    const u16* W0 = p.A5 + (r0       )*1024 + kw + lofs;
    const u16* W1 = p.A5 + (r0 + 1024)*1024 + kw + lofs;
    const u16* W2 = p.A5 + (r0 + 2048)*1024 + kw + lofs;
    gemm3<8>(qn + (size_t)(b0+l15)*DD + kw + lofs, DD, W0, W1, W2, acc);
  }
  if (kq == 1) parkAcc48(LI0, acc, l15, l4, false);
  if (kq == 3) parkAcc48(LI1, acc, l15, l4, false);
  __syncthreads();
  if (kq == 0) parkAcc48(LI0, acc, l15, l4, true);
  if (kq == 2) parkAcc48(LI1, acc, l15, l4, true);
  zeroAcc(acc);
  if (td > 0) { // h-part: e_{td-1}
    const u16* ebr = (t & 1) ? p.eb1 : p.eb0;
    const int kw = kq*256;
    const u16* W0 = p.A6 + (r0       )*1024 + kw + lofs;
    const u16* W1 = p.A6 + (r0 + 1024)*1024 + kw + lofs;
    const u16* W2 = p.A6 + (r0 + 2048)*1024 + kw + lofs;
    gemm3<8>(ebr + (size_t)(b0+l15)*DD + kw + lofs, DD, W0, W1, W2, acc);
  }
  if (kq == 1) parkAcc48(LH0, acc, l15, l4, false);
  if (kq == 3) parkAcc48(LH1, acc, l15, l4, false);
  __syncthreads();
  if (kq == 0) parkAcc48(LH0, acc, l15, l4, true);
  if (kq == 2) parkAcc48(LH1, acc, l15, l4, true);
  __syncthreads();
  if (tid < 64) {
    const int lb = tid >> 1, b = b0 + lb, jjb = (tid & 1) * 8;
    const float* i0 = LI0 + lb*48; const float* i1 = LI1 + lb*48;
    const float* h0 = LH0 + lb*48; const float* h1 = LH1 + lb*48;
    float ev8[8];
    #pragma unroll
    for (int i = 0; i < 8; ++i) {
      const int jj = jjb + i, j = j0 + jj;
      const float ir = i0[jj]    + i1[jj]    + p.bihe[j];
      const float iz = i0[16+jj] + i1[16+jj] + p.bihe[1024+j];
      const float in_= i0[32+jj] + i1[32+jj] + p.bihe[2048+j];
      const float hr = h0[jj]    + h1[jj]    + p.bhhe[j];
      const float hz = h0[16+jj] + h1[16+jj] + p.bhhe[1024+j];
      const float hn = h0[32+jj] + h1[32+jj] + p.bhhe[2048+j];
      const float r_ = sigm(ir + hr);
      const float z_ = sigm(iz + hz);
      const float n_ = tanh_(in_ + r_*hn);
      const float ep = p.ef[(size_t)b*DD + j];
      const float ev = (1.f - z_)*n_ + z_*ep;
      p.ef[(size_t)b*DD + j] = ev;
      ev8[i] = ev;
    }
    float* orow = p.out + (size_t)td*BB*DD + (size_t)b*DD + j0 + jjb;
    *(f32x4*)orow       = (f32x4){ev8[0], ev8[1], ev8[2], ev8[3]};
    *(f32x4*)(orow + 4) = (f32x4){ev8[4], ev8[5], ev8[6], ev8[7]};
    u16* ebw = ((t-1) & 1) ? p.eb1 : p.eb0;
    bf16x8 ee;
    #pragma unroll
    for (int i = 0; i < 8; ++i) ee[i] = (short)f2b(ev8[i]);
    *(bf16x8*)(ebw + (size_t)b*DD + j0 + jjb) = ee;
  }
}

// ---- fused party GRU + inline online-softmax attention (128 blocks: 16 cols x 32 batch) ----
__device__ void fusedP(const DPar& p, int t, int bj, int bh, char* ldsraw) {
  float* LI0 = (float*)ldsraw;     // GW = ghist(t-1) @ Wp2 slice
  float* LI1 = LI0 + 1536;
  float* LH0 = LI1 + 1536;         // GHP = qsel_t @ Whh_p slice
  float* LH1 = LH0 + 1536;
  const int tid = (int)threadIdx.x;
  const int kq = tid >> 6;
  const int lane = tid & 63, l15 = lane & 15, l4 = lane >> 4;
  const int lofs = l4 * 8;
  const int j0 = bj * 16;
  const int b0 = bh * 32;
  const size_t r0 = (size_t)(j0 + l15);
  const u16* qsel = (t & 1) ? p.qsel1 : p.qsel0;
  f32x4 acc[2][3];
  zeroAcc(acc);
  if (t) { // GW: ghist(t-1) against second K-half of A3
    const int kw = 1024 + kq*256;
    const u16* W0 = p.A3 + (r0       )*2048 + kw + lofs;
    const u16* W1 = p.A3 + (r0 + 1024)*2048 + kw + lofs;
    const u16* W2 = p.A3 + (r0 + 2048)*2048 + kw + lofs;
    gemm3<8>(p.ghist + (size_t)(t-1)*BB*DD + (size_t)(b0+l15)*DD + kq*256 + lofs, DD, W0, W1, W2, acc);
  }
  if (kq == 1) parkAcc48(LI0, acc, l15, l4, false);
  if (kq == 3) parkAcc48(LI1, acc, l15, l4, false);
  __syncthreads();
  if (kq == 0) parkAcc48(LI0, acc, l15, l4, true);
  if (kq == 2) parkAcc48(LI1, acc, l15, l4, true);
  zeroAcc(acc);
  { // GHP: qsel_t @ Whh_p^T (A4, K=1024 quarters)
    const int kw = kq*256;
    const u16* W0 = p.A4 + (r0       )*1024 + kw + lofs;
    const u16* W1 = p.A4 + (r0 + 1024)*1024 + kw + lofs;
    const u16* W2 = p.A4 + (r0 + 2048)*1024 + kw + lofs;
    gemm3<8>(qsel + (size_t)(b0+l15)*DD + kw + lofs, DD, W0, W1, W2, acc);
  }
  if (kq == 1) parkAcc48(LH0, acc, l15, l4, false);
  if (kq == 3) parkAcc48(LH1, acc, l15, l4, false);
  __syncthreads();
  if (kq == 0) parkAcc48(LH0, acc, l15, l4, true);
  if (kq == 2) parkAcc48(LH1, acc, l15, l4, true);
  __syncthreads();
  if (tid < 64) {
    const int lb = tid >> 1, b = b0 + lb, jjb = (tid & 1) * 8;
    float mN = -1e30f, Zn = 0.f, scl = 0.f, wn = 0.f, invZ = 0.f;
    if (t > 0) {
      const float* sp = p.scoresP + (size_t)(t-1)*64*BB + b;
      float s = 0.f;
      #pragma unroll
      for (int pp = 0; pp < 64; ++pp) s += sp[pp*BB];
      const float mo = ((t-1) & 1 ? p.m1 : p.m0)[b];
      const float Zo = ((t-1) & 1 ? p.Z1 : p.Z0)[b];
      mN  = fmaxf(mo, s);
      scl = __expf(mo - mN);
      wn  = __expf(s - mN);
      Zn  = Zo*scl + wn;
      invZ = 1.f / Zn;
    }
    float* Nw = (t & 1) ? p.N1 : p.N0;
    const float* Nr = (t & 1) ? p.N0 : p.N1;
    const int spkc = p.spk[t*BB + b];
    const int spkn = (t+1 < TT) ? p.spk[(t+1)*BB + b] : spkc;
    float* prow = p.parties + (size_t)(b*2 + spkc)*DD;
    const float* orow = p.parties + (size_t)(b*2 + spkn)*DD;
    const float* Gia = ((t & 1) ? p.GIPa1 : p.GIPa0) + (size_t)b*G3;
    const float* i0 = LI0 + lb*48; const float* i1 = LI1 + lb*48;
    const float* h0 = LH0 + lb*48; const float* h1 = LH1 + lb*48;
    u16* qselw = ((t+1) & 1) ? p.qsel1 : p.qsel0;
    u16* qneww = (t & 1) ? p.qnew1 : p.qnew0;
    float qn8[8], qs8[8];
    #pragma unroll
    for (int i = 0; i < 8; ++i) {
      const int jj = jjb + i, j = j0 + jj;
      float gipb[3];
      #pragma unroll
      for (int g = 0; g < 3; ++g) {
        const size_t col = (size_t)g*1024 + j;
        const float GW = i0[g*16+jj] + i1[g*16+jj];
        float Nn = 0.f;
        if (t > 0) Nn = Nr[(size_t)b*G3 + col]*scl + wn*GW;
        Nw[(size_t)b*G3 + col] = Nn;
        gipb[g] = Nn * invZ;
      }
      const float gi_r = Gia[j]      + gipb[0] + p.bihp[j];
      const float gi_z = Gia[1024+j] + gipb[1] + p.bihp[1024+j];
      const float gi_n = Gia[2048+j] + gipb[2] + p.bihp[2048+j];
      const float gh_r = h0[jj]    + h1[jj]    + p.bhhp[j];
      const float gh_z = h0[16+jj] + h1[16+jj] + p.bhhp[1024+j];
      const float gh_n = h0[32+jj] + h1[32+jj] + p.bhhp[2048+j];
      const float r_ = sigm(gi_r + gh_r);
      const float z_ = sigm(gi_z + gh_z);
      const float n_ = tanh_(gi_n + r_*gh_n);
      const float h  = prow[j];
      const float qv = (1.f - z_)*n_ + z_*h;
      prow[j] = qv;
      qn8[i] = qv;
      qs8[i] = (spkn == spkc) ? qv : orow[j];
    }
    if (bj == 0 && (tid & 1) == 0) {
      ((t & 1) ? p.m1 : p.m0)[b] = mN;
      ((t & 1) ? p.Z1 : p.Z0)[b] = Zn;
    }
    bf16x8 qn, qs;
    #pragma unroll
    for (int i = 0; i < 8; ++i) { qn[i] = (short)f2b(qn8[i]); qs[i] = (short)f2b(qs8[i]); }
    *(bf16x8*)(qneww + (size_t)b*DD + j0 + jjb) = qn;
    *(bf16x8*)(qselw + (size_t)b*DD + j0 + jjb) = qs;
  }
}

// ---- 64-col x 32-batch GEMM tile (2 K-halves x 2 N-halves, 2 bt), for GIPa ----
template<typename TA>
__device__ __attribute__((noinline)) void gemm_frag(
    const TA* __restrict__ A, const u16* __restrict__ W, int ldW,
    int k0, int n0, int b0, float* __restrict__ C, float* red) {
  const int tid = threadIdx.x;
  const int wv  = tid >> 6;
  const int kh  = wv >> 1;
  const int nh  = wv & 1;
  const int lane = tid & 63;
  const int l15 = lane & 15;
  const int l4  = lane >> 4;
  const TA*  Ab = A + (size_t)(b0 + l15) * DD + kh * 512 + l4 * 8;
  const u16* Wb = W + (size_t)(n0 + nh*32 + l15) * ldW + k0 + kh * 512 + l4 * 8;

  f32x4 acc[2][2];
  #pragma unroll
  for (int i = 0; i < 2; ++i) { acc[i][0] = (f32x4){0,0,0,0}; acc[i][1] = (f32x4){0,0,0,0}; }

  bf16x8 af[5][2], wf[5][2];
  #pragma unroll
  for (int i = 0; i < 4; ++i) {
    const int ko = i * 32;
    loadA(af[i][0], Ab + ko);
    loadA(af[i][1], Ab + (size_t)16*DD + ko);
    wf[i][0] = *(const bf16x8*)(Wb + ko);
    wf[i][1] = *(const bf16x8*)(Wb + (size_t)16*ldW + ko);
  }
  #pragma unroll
  for (int kt = 0; kt < 16; ++kt) {
    const int cur = kt % 5;
    const int pft = kt + 4;
    if (pft < 16) {
      const int nb = pft % 5;
      const int ko = pft * 32;
      loadA(af[nb][0], Ab + ko);
      loadA(af[nb][1], Ab + (size_t)16*DD + ko);
      wf[nb][0] = *(const bf16x8*)(Wb + ko);
      wf[nb][1] = *(const bf16x8*)(Wb + (size_t)16*ldW + ko);
    }
    #pragma unroll
    for (int bt = 0; bt < 2; ++bt) {
      acc[bt][0] = __builtin_amdgcn_mfma_f32_16x16x32_bf16(af[cur][bt], wf[cur][0], acc[bt][0], 0,0,0);
      acc[bt][1] = __builtin_amdgcn_mfma_f32_16x16x32_bf16(af[cur][bt], wf[cur][1], acc[bt][1], 0,0,0);
    }
  }
  if (kh == 1) {
    #pragma unroll
    for (int bt = 0; bt < 2; ++bt)
      #pragma unroll
      for (int nt = 0; nt < 2; ++nt)
        #pragma unroll
        for (int q = 0; q < 4; ++q)
          red[(bt*16 + l4*4 + q)*64 + nh*32 + nt*16 + l15] = acc[bt][nt][q];
  }
  __syncthreads();
  if (kh == 0) {
    #pragma unroll
    for (int bt = 0; bt < 2; ++bt)
      #pragma unroll
      for (int nt = 0; nt < 2; ++nt)
        #pragma unroll
        for (int q = 0; q < 4; ++q) {
          const int row = bt*16 + l4*4 + q;
          const int col = nh*32 + nt*16 + l15;
          C[(size_t)(b0 + row)*G3 + n0 + col] = acc[bt][nt][q] + red[row*64 + col];
        }
  }
}

// ---- one dispatch per step. XCD-pairing: batch-halves of the same col-slice get
// blockIdx values 64 (or 48) apart => same XCD under round-robin => weight reads
// of the second half hit that XCD's L2 instead of re-fetching. ----
__global__ void __launch_bounds__(256) k_step(DPar p, int t) {
  __shared__ __align__(16) char lds[24576];
  const int blk = (int)blockIdx.x;
  if (blk < 128)       fusedG(p, t, blk & 63, blk >> 6, lds);
  else if (blk < 256)  { if (t) fusedE(p, t, (blk-128) & 63, (blk-128) >> 6, lds); }
  else if (blk < 384)  fusedP(p, t, (blk-256) & 63, (blk-256) >> 6, lds);
  else { if (t + 1 < TT) {
           const int r = blk - 384;           // 0..95: bj = r%48, bh = r/48 (48 % 8 == 0)
           gemm_frag(p.feat + (size_t)(t+1)*BB*DD, p.A3, 2048, 0, (r % 48)*64, (r / 48)*32,
                     ((t+1)&1) ? p.GIPa1 : p.GIPa0, (float*)lds);
         } }
}

// ---- prologue: GIPa(0) ----
__global__ void __launch_bounds__(256) kPre(DPar p) {
  __shared__ __align__(16) float red[2048];
  const int r = (int)blockIdx.x;
  gemm_frag(p.feat, p.A3, 2048, 0, (r % 48)*64, (r / 48)*32, p.GIPa0, red);
}

// ---- epilogue: emotion step 127 ----
__global__ void __launch_bounds__(256) kEpi(DPar p) {
  __shared__ __align__(16) char lds[24576];
  fusedE(p, TT, (int)blockIdx.x & 63, (int)blockIdx.x >> 6, lds);
}

// ---- setup: weight fp32 -> bf16 cast + state zero + speaker idx (every launch) ----
__global__ void setupK(const float* __restrict__ Wg, const float* __restrict__ Whg,
                       const float* __restrict__ Wp, const float* __restrict__ Whp,
                       const float* __restrict__ We, const float* __restrict__ Whe,
                       u16* A1, u16* A2, u16* A3, u16* A4, u16* A5, u16* A6,
                       float* parties, float* gf, float* ef,
                       u16* qsel0, u16* qsel1, u16* qnew0, u16* qnew1, u16* eb0, u16* eb1,
                       const float* spkOH, int* spk) {
  long gid = (long)blockIdx.x*256 + threadIdx.x;
  if (gid < BB*2*DD) parties[gid] = 0.f;
  if (gid < BB*DD) {
    gf[gid] = 0.f; ef[gid] = 0.f;
    qsel0[gid] = 0; qsel1[gid] = 0; qnew0[gid] = 0; qnew1[gid] = 0; eb0[gid] = 0; eb1[gid] = 0;
  }
  if (gid < TT*BB) spk[gid] = (spkOH[(size_t)gid*2 + 1] > 0.5f) ? 1 : 0;
  const long n1 = (long)G3*2048/4, n2 = (long)G3*1024/4;
  const long tot = 2*n1 + 4*n2;
  const long stride = (long)gridDim.x*256;
  for (long i = gid; i < tot; i += stride) {
    const float* src; u16* dst; long o = i;
    if (o < n1) { src = Wg;  dst = A1; }
    else { o -= n1;
      if (o < n2) { src = Whg; dst = A2; }
      else { o -= n2;
        if (o < n1) { src = Wp; dst = A3; }
        else { o -= n1;
          if (o < n2) { src = Whp; dst = A4; }
          else { o -= n2;
            if (o < n2) { src = We; dst = A5; }
            else { o -= n2; src = Whe; dst = A6; }
          }
        }
      }
    }
    f32x4 v = *(const f32x4*)(src + o*4);
    s16x4 w;
    w[0] = (short)f2b(v[0]); w[1] = (short)f2b(v[1]);
    w[2] = (short)f2b(v[2]); w[3] = (short)f2b(v[3]);
    *(s16x4*)(dst + o*4) = w;
  }
}

extern "C" void kernel_launch(void* const* d_in, const int* in_sizes, int n_in,
                              void* d_out, int out_size, void* d_ws, size_t ws_size,
                              hipStream_t stream) {
  const float* feat  = (const float*)d_in[0];
  const float* spkOH = (const float*)d_in[1];
  const float* Wih_g = (const float*)d_in[2];
  const float* Whh_g = (const float*)d_in[3];
  const float* bih_g = (const float*)d_in[4];
  const float* bhh_g = (const float*)d_in[5];
  const float* Wih_p = (const float*)d_in[6];
  const float* Whh_p = (const float*)d_in[7];
  const float* bih_p = (const float*)d_in[8];
  const float* bhh_p = (const float*)d_in[9];
  const float* Wih_e = (const float*)d_in[10];
  const float* Whh_e = (const float*)d_in[11];
  const float* bih_e = (const float*)d_in[12];
  const float* bhh_e = (const float*)d_in[13];
  const float* watt  = (const float*)d_in[14];

  char* w = (char*)d_ws;
  auto alloc = [&](size_t bytes) -> char* {
    char* r = w; w += (bytes + 255) & ~(size_t)255; return r;
  };
  u16* ghist = (u16*)alloc((size_t)TT*BB*DD*2);
  float* scoresP = (float*)alloc((size_t)TT*64*BB*4);
  u16* qsel0 = (u16*)alloc((size_t)BB*DD*2);
  u16* qsel1 = (u16*)alloc((size_t)BB*DD*2);
  u16* qnew0 = (u16*)alloc((size_t)BB*DD*2);
  u16* qnew1 = (u16*)alloc((size_t)BB*DD*2);
  u16* eb0   = (u16*)alloc((size_t)BB*DD*2);
  u16* eb1   = (u16*)alloc((size_t)BB*DD*2);
  float* parties = (float*)alloc((size_t)BB*2*DD*4);
  float* gf  = (float*)alloc((size_t)BB*DD*4);
  float* ef  = (float*)alloc((size_t)BB*DD*4);
  float* GIPa0 = (float*)alloc((size_t)BB*G3*4);
  float* GIPa1 = (float*)alloc((size_t)BB*G3*4);
  float* N0 = (float*)alloc((size_t)BB*G3*4);
  float* N1 = (float*)alloc((size_t)BB*G3*4);
  float* m0 = (float*)alloc(BB*4);
  float* m1 = (float*)alloc(BB*4);
  float* Z0 = (float*)alloc(BB*4);
  float* Z1 = (float*)alloc(BB*4);
  int* spk    = (int*)alloc((size_t)TT*BB*4);
  u16* A1 = (u16*)alloc((size_t)G3*2048*2);
  u16* A2 = (u16*)alloc((size_t)G3*1024*2);
  u16* A3 = (u16*)alloc((size_t)G3*2048*2);
  u16* A4 = (u16*)alloc((size_t)G3*1024*2);
  u16* A5 = (u16*)alloc((size_t)G3*1024*2);
  u16* A6 = (u16*)alloc((size_t)G3*1024*2);
  const size_t need = (size_t)(w - (char*)d_ws);   // ~71 MB < proven 75.5 MB bound
  if (ws_size < need) return;   // fail validation visibly rather than fault

  hipLaunchKernelGGL(setupK, dim3(2048), dim3(256), 0, stream,
                     Wih_g, Whh_g, Wih_p, Whh_p, Wih_e, Whh_e,
                     A1, A2, A3, A4, A5, A6,
                     parties, gf, ef, qsel0, qsel1, qnew0, qnew1, eb0, eb1, spkOH, spk);

  DPar p;
  p.A1 = A1; p.A2 = A2; p.A3 = A3; p.A4 = A4; p.A5 = A5; p.A6 = A6;
  p.feat = feat;
  p.ghist = ghist; p.qsel0 = qsel0; p.qsel1 = qsel1; p.qnew0 = qnew0; p.qnew1 = qnew1;
  p.eb0 = eb0; p.eb1 = eb1;
  p.scoresP = scoresP; p.parties = parties; p.gf = gf; p.ef = ef;
  p.GIPa0 = GIPa0; p.GIPa1 = GIPa1;
  p.N0 = N0; p.N1 = N1; p.m0 = m0; p.m1 = m1; p.Z0 = Z0; p.Z1 = Z1;
  p.bihg = bih_g; p.bhhg = bhh_g; p.bihp = bih_p; p.bhhp = bhh_p;
  p.bihe = bih_e; p.bhhe = bhh_e; p.watt = watt;
  p.spk = spk; p.out = (float*)d_out;

  hipLaunchKernelGGL(kPre, dim3(96), dim3(256), 0, stream, p);
  for (int t = 0; t < TT; ++t)
    hipLaunchKernelGGL(k_step, dim3(480), dim3(256), 0, stream, p, t);
  hipLaunchKernelGGL(kEpi, dim3(128), dim3(256), 0, stream, p);
}